// Round 10
// baseline (216.280 us; speedup 1.0000x reference)
//
#include <hip/hip_runtime.h>
#include <hip/hip_bf16.h>

#define D 64
#define RB 128           // rows per coarse bucket (b = row>>7)
#define RB_SHIFT 7
#define COL_BITS 18      // n_total = 150001 < 2^18
#define COL_MASK 0x3FFFF
#define CHUNK 4096       // edges per partition block (489 blocks)

// bf16 helpers (round-to-nearest-even; bf16->f32 exact)
__device__ __forceinline__ unsigned f2bf(float f) {
    unsigned u = __float_as_uint(f);
    u += 0x7fff + ((u >> 16) & 1);
    return u >> 16;
}
__device__ __forceinline__ float bf_lo(unsigned w) {   // low bf16 of packed u32
    return __uint_as_float(w << 16);
}
__device__ __forceinline__ float bf_hi(unsigned w) {   // high bf16 of packed u32
    return __uint_as_float(w & 0xffff0000u);
}

// ---------------------------------------------------------------------------
// one-time: concat f32 tables -> bf16 table (n_total x 64)
__global__ void convert_kernel(const float* __restrict__ user_emb,
                               const float* __restrict__ item_emb,
                               unsigned short* __restrict__ tbl,
                               int n_user_rows, int n_total) {
    size_t t = (size_t)blockIdx.x * blockDim.x + threadIdx.x;
    size_t total4 = (size_t)n_total * (D / 4);
    size_t user4 = (size_t)n_user_rows * (D / 4);
    for (size_t i = t; i < total4; i += (size_t)gridDim.x * blockDim.x) {
        float4 v = (i < user4) ? reinterpret_cast<const float4*>(user_emb)[i]
                               : reinterpret_cast<const float4*>(item_emb)[i - user4];
        uint2 o;
        o.x = f2bf(v.x) | (f2bf(v.y) << 16);
        o.y = f2bf(v.z) | (f2bf(v.w) << 16);
        reinterpret_cast<uint2*>(tbl)[i] = o;
    }
}

// ---------------------------------------------------------------------------
// Fused fill: per-chunk histogram + LDS scan + bucket-sorted write into a
// BLOCK-PRIVATE span of stage (streaming stores, no cross-block lines).
// Exports local offsets loff[blk][0..nb], loff[blk][nb] = #edges in chunk.
__global__ void fill_sorted_kernel(const int* __restrict__ row,
                                   const int* __restrict__ col,
                                   const float* __restrict__ val,
                                   int2* __restrict__ stage,
                                   int* __restrict__ loff,
                                   int n_edges, int nb) {
    __shared__ int h[2048];        // hist -> scanned offsets -> cursors
    __shared__ int partial[256];
    int blk = blockIdx.x;
    int tid = threadIdx.x;
    for (int i = tid; i < nb; i += 256) h[i] = 0;
    __syncthreads();
    int s = blk * CHUNK;
    int e = min(s + CHUNK, n_edges);
    // pass 1: local histogram
    for (int k = s + tid; k < e; k += 256)
        atomicAdd(&h[row[k] >> RB_SHIFT], 1);
    __syncthreads();
    // exclusive scan of h[0..nb) (8 entries/thread + block scan of partials)
    int local[8];
    int sum = 0;
#pragma unroll
    for (int j = 0; j < 8; ++j) {
        int idx = tid * 8 + j;
        int v = (idx < nb) ? h[idx] : 0;
        local[j] = sum;
        sum += v;
    }
    partial[tid] = sum;
    __syncthreads();
    for (int off = 1; off < 256; off <<= 1) {
        int v = (tid >= off) ? partial[tid - off] : 0;
        __syncthreads();
        partial[tid] += v;
        __syncthreads();
    }
    int prefix = (tid == 0) ? 0 : partial[tid - 1];
    __syncthreads();
#pragma unroll
    for (int j = 0; j < 8; ++j) {
        int idx = tid * 8 + j;
        if (idx < nb) h[idx] = prefix + local[j];
    }
    __syncthreads();
    // export local offsets (coalesced)
    int* lrow = loff + (size_t)blk * (nb + 1);
    for (int i = tid; i < nb; i += 256) lrow[i] = h[i];
    if (tid == 0) lrow[nb] = e - s;
    __syncthreads();
    // pass 2: rank via LDS cursors, write bucket-sorted into private span
    int2* span = stage + (size_t)blk * CHUNK;
    for (int k = s + tid; k < e; k += 256) {
        int r = row[k];
        int b = r >> RB_SHIFT;
        int pos = atomicAdd(&h[b], 1);
        span[pos] = make_int2(col[k] | ((r & (RB - 1)) << COL_BITS), __float_as_int(val[k]));
    }
}

// tot[b] = sum over blk of (loff[blk][b+1]-loff[blk][b]) — ONE WAVE per bucket
__global__ void col_sum_kernel(const int* __restrict__ loff, int* __restrict__ tot,
                               int nb, int nblk) {
    int w = (blockIdx.x * blockDim.x + threadIdx.x) >> 6;
    int lane = threadIdx.x & 63;
    if (w >= nb) return;
    int s = 0;
    for (int blk = lane; blk < nblk; blk += 64) {
        const int* lrow = loff + (size_t)blk * (nb + 1);
        s += lrow[w + 1] - lrow[w];
    }
    for (int off = 32; off > 0; off >>= 1)
        s += __shfl_down(s, off, 64);
    if (lane == 0) tot[w] = s;
}

// single-block exclusive scan of tot[0..nb) -> coff, coff[nb]=total
__global__ void scan_tot_kernel(const int* __restrict__ tot, int* __restrict__ coff,
                                int nb) {
    __shared__ int lds[256];
    int tid = threadIdx.x;
    int local[8];
    int sum = 0;
#pragma unroll
    for (int j = 0; j < 8; ++j) {
        int idx = tid * 8 + j;
        int v = (idx < nb) ? tot[idx] : 0;
        local[j] = sum;
        sum += v;
    }
    lds[tid] = sum;
    __syncthreads();
    for (int off = 1; off < 256; off <<= 1) {
        int v = (tid >= off) ? lds[tid - off] : 0;
        __syncthreads();
        lds[tid] += v;
        __syncthreads();
    }
    int prefix = (tid == 0) ? 0 : lds[tid - 1];
#pragma unroll
    for (int j = 0; j < 8; ++j) {
        int idx = tid * 8 + j;
        if (idx < nb) coff[idx] = prefix + local[j];
    }
    if (tid == 255) coff[nb] = lds[255];
}

// per-bucket: gather this bucket's runs from all block spans, sort by row,
// emit row-level offsets + row-sorted pairs. Runs/loff are L2-resident.
__global__ void bucket_finalize_kernel(const int* __restrict__ coff,
                                       const int* __restrict__ loff,
                                       const int2* __restrict__ stage,
                                       int* __restrict__ offsets,
                                       int2* __restrict__ pairs,
                                       int n_total, int n_edges, int nb, int nblk) {
    __shared__ int sc[RB];
    __shared__ int cur[RB];
    int b = blockIdx.x;
    int tid = threadIdx.x;
    int s = coff[b];
    if (tid < RB) sc[tid] = 0;
    __syncthreads();
    // pass 1: count rows across this bucket's runs
    for (int blk = tid; blk < nblk; blk += 256) {
        const int* lrow = loff + (size_t)blk * (nb + 1);
        int rs = lrow[b], re = lrow[b + 1];
        const int2* span = stage + (size_t)blk * CHUNK;
        for (int k = rs; k < re; ++k)
            atomicAdd(&sc[span[k].x >> COL_BITS], 1);
    }
    __syncthreads();
    // inclusive scan of 128 counters
    for (int off = 1; off < RB; off <<= 1) {
        int v = (tid < RB && tid >= off) ? sc[tid - off] : 0;
        __syncthreads();
        if (tid < RB) sc[tid] += v;
        __syncthreads();
    }
    if (tid < RB) {
        int excl = (tid == 0) ? 0 : sc[tid - 1];
        int r = b * RB + tid;
        if (r < n_total) offsets[r] = s + excl;
        cur[tid] = s + excl;
    }
    __syncthreads();
    // pass 2: scatter into the bucket's contiguous pairs span
    for (int blk = tid; blk < nblk; blk += 256) {
        const int* lrow = loff + (size_t)blk * (nb + 1);
        int rs = lrow[b], re = lrow[b + 1];
        const int2* span = stage + (size_t)blk * CHUNK;
        for (int k = rs; k < re; ++k) {
            int2 p = span[k];
            int rl = p.x >> COL_BITS;
            int pos = atomicAdd(&cur[rl], 1);
            pairs[pos] = make_int2(p.x & COL_MASK, p.y);
        }
    }
    if (b == 0 && tid == 0) offsets[n_total] = n_edges;
}

// ---------------------------------------------------------------------------
// gather spmm (bf16 src/dst, f32 accum): ONE 8-LANE GROUP PER ROW, edge loop
// 4-way unrolled so 4 independent row gathers are in flight per group.
__global__ void spmm_gather_kernel(const int* __restrict__ offsets,
                                   const int2* __restrict__ pairs,
                                   const unsigned short* __restrict__ src,
                                   unsigned short* __restrict__ dst, int n_total) {
    int t = blockIdx.x * blockDim.x + threadIdx.x;
    int r = t >> 3;          // destination row
    int sub = t & 7;         // 16 B slice of the row
    if (r >= n_total) return;
    int start = offsets[r];
    int end = offsets[r + 1];
    const uint4* s4 = reinterpret_cast<const uint4*>(src);
    float a0 = 0.f, a1 = 0.f, a2 = 0.f, a3 = 0.f,
          a4 = 0.f, a5 = 0.f, a6 = 0.f, a7 = 0.f;
    int k = start;
    for (; k + 4 <= end; k += 4) {
        int2 p0 = pairs[k + 0];
        int2 p1 = pairs[k + 1];
        int2 p2 = pairs[k + 2];
        int2 p3 = pairs[k + 3];
        uint4 r0 = s4[(size_t)p0.x * 8 + sub];
        uint4 r1 = s4[(size_t)p1.x * 8 + sub];
        uint4 r2 = s4[(size_t)p2.x * 8 + sub];
        uint4 r3 = s4[(size_t)p3.x * 8 + sub];
        float w0 = __int_as_float(p0.y), w1 = __int_as_float(p1.y);
        float w2 = __int_as_float(p2.y), w3 = __int_as_float(p3.y);
        a0 += w0 * bf_lo(r0.x); a1 += w0 * bf_hi(r0.x);
        a2 += w0 * bf_lo(r0.y); a3 += w0 * bf_hi(r0.y);
        a4 += w0 * bf_lo(r0.z); a5 += w0 * bf_hi(r0.z);
        a6 += w0 * bf_lo(r0.w); a7 += w0 * bf_hi(r0.w);
        a0 += w1 * bf_lo(r1.x); a1 += w1 * bf_hi(r1.x);
        a2 += w1 * bf_lo(r1.y); a3 += w1 * bf_hi(r1.y);
        a4 += w1 * bf_lo(r1.z); a5 += w1 * bf_hi(r1.z);
        a6 += w1 * bf_lo(r1.w); a7 += w1 * bf_hi(r1.w);
        a0 += w2 * bf_lo(r2.x); a1 += w2 * bf_hi(r2.x);
        a2 += w2 * bf_lo(r2.y); a3 += w2 * bf_hi(r2.y);
        a4 += w2 * bf_lo(r2.z); a5 += w2 * bf_hi(r2.z);
        a6 += w2 * bf_lo(r2.w); a7 += w2 * bf_hi(r2.w);
        a0 += w3 * bf_lo(r3.x); a1 += w3 * bf_hi(r3.x);
        a2 += w3 * bf_lo(r3.y); a3 += w3 * bf_hi(r3.y);
        a4 += w3 * bf_lo(r3.z); a5 += w3 * bf_hi(r3.z);
        a6 += w3 * bf_lo(r3.w); a7 += w3 * bf_hi(r3.w);
    }
    for (; k < end; ++k) {
        int2 p = pairs[k];
        float w = __int_as_float(p.y);
        uint4 raw = s4[(size_t)p.x * 8 + sub];
        a0 += w * bf_lo(raw.x); a1 += w * bf_hi(raw.x);
        a2 += w * bf_lo(raw.y); a3 += w * bf_hi(raw.y);
        a4 += w * bf_lo(raw.z); a5 += w * bf_hi(raw.z);
        a6 += w * bf_lo(raw.w); a7 += w * bf_hi(raw.w);
    }
    uint4 o;
    o.x = f2bf(a0) | (f2bf(a1) << 16);
    o.y = f2bf(a2) | (f2bf(a3) << 16);
    o.z = f2bf(a4) | (f2bf(a5) << 16);
    o.w = f2bf(a6) | (f2bf(a7) << 16);
    reinterpret_cast<uint4*>(dst + (size_t)r * D)[sub] = o;
}

// ---------------------------------------------------------------------------
// layer 0: write batch rows straight from the f32 source tables
__global__ void gather_init_kernel(const int* __restrict__ users,
                                   const int* __restrict__ items,
                                   const float* __restrict__ user_emb,
                                   const float* __restrict__ item_emb,
                                   float* __restrict__ u_acc,
                                   float* __restrict__ v_acc, int batch) {
    int t = blockIdx.x * blockDim.x + threadIdx.x;
    int b = t >> 4;
    int sub = t & 15;
    if (b >= batch) return;
    reinterpret_cast<float4*>(u_acc)[(size_t)b * 16 + sub] =
        reinterpret_cast<const float4*>(user_emb)[(size_t)users[b] * 16 + sub];
    reinterpret_cast<float4*>(v_acc)[(size_t)b * 16 + sub] =
        reinterpret_cast<const float4*>(item_emb)[(size_t)items[b] * 16 + sub];
}

// layers 1,2: accumulate batch rows from bf16 buf into f32 acc
__global__ void gather_acc_kernel(const int* __restrict__ users,
                                  const int* __restrict__ items,
                                  const unsigned short* __restrict__ buf,
                                  float* __restrict__ u_acc,
                                  float* __restrict__ v_acc,
                                  int batch, int n_user_rows) {
    int t = blockIdx.x * blockDim.x + threadIdx.x;
    int b = t >> 4;
    int sub = t & 15;
    if (b >= batch) return;
    uint2 ur = reinterpret_cast<const uint2*>(buf + (size_t)users[b] * D)[sub];
    uint2 vr = reinterpret_cast<const uint2*>(buf + (size_t)(n_user_rows + items[b]) * D)[sub];
    float4* up = reinterpret_cast<float4*>(u_acc) + (size_t)b * 16 + sub;
    float4* vp = reinterpret_cast<float4*>(v_acc) + (size_t)b * 16 + sub;
    float4 a = *up, c = *vp;
    a.x += bf_lo(ur.x); a.y += bf_hi(ur.x);
    a.z += bf_lo(ur.y); a.w += bf_hi(ur.y);
    c.x += bf_lo(vr.x); c.y += bf_hi(vr.x);
    c.z += bf_lo(vr.y); c.w += bf_hi(vr.y);
    *up = a;
    *vp = c;
}

// ---------------------------------------------------------------------------
// Fused final stage: per batch element, compute layer-3 ONLY for its user row
// and item row, add to the layer-0..2 accumulators, dot, BCE, reduce.
__global__ void batch_l3_loss_kernel(const int* __restrict__ users,
                                     const int* __restrict__ items,
                                     const int* __restrict__ offsets,
                                     const int2* __restrict__ pairs,
                                     const unsigned short* __restrict__ buf,
                                     const float* __restrict__ u_acc,
                                     const float* __restrict__ v_acc,
                                     const float* __restrict__ labels,
                                     float* __restrict__ out,
                                     int batch, int n_user_rows) {
    int t = blockIdx.x * blockDim.x + threadIdx.x;
    int b = t >> 3;
    int sub = t & 7;
    const uint4* s4 = reinterpret_cast<const uint4*>(buf);
    float lb = 0.0f;
    if (b < batch) {
        float au[8] = {0.f}, av[8] = {0.f};
        for (int side = 0; side < 2; ++side) {
            int row = (side == 0) ? users[b] : (n_user_rows + items[b]);
            float* acc = (side == 0) ? au : av;
            int k = offsets[row];
            int end = offsets[row + 1];
            for (; k + 2 <= end; k += 2) {
                int2 p0 = pairs[k + 0];
                int2 p1 = pairs[k + 1];
                uint4 r0 = s4[(size_t)p0.x * 8 + sub];
                uint4 r1 = s4[(size_t)p1.x * 8 + sub];
                float w0 = __int_as_float(p0.y), w1 = __int_as_float(p1.y);
                acc[0] += w0 * bf_lo(r0.x) + w1 * bf_lo(r1.x);
                acc[1] += w0 * bf_hi(r0.x) + w1 * bf_hi(r1.x);
                acc[2] += w0 * bf_lo(r0.y) + w1 * bf_lo(r1.y);
                acc[3] += w0 * bf_hi(r0.y) + w1 * bf_hi(r1.y);
                acc[4] += w0 * bf_lo(r0.z) + w1 * bf_lo(r1.z);
                acc[5] += w0 * bf_hi(r0.z) + w1 * bf_hi(r1.z);
                acc[6] += w0 * bf_lo(r0.w) + w1 * bf_lo(r1.w);
                acc[7] += w0 * bf_hi(r0.w) + w1 * bf_hi(r1.w);
            }
            for (; k < end; ++k) {
                int2 p = pairs[k];
                float w = __int_as_float(p.y);
                uint4 raw = s4[(size_t)p.x * 8 + sub];
                acc[0] += w * bf_lo(raw.x); acc[1] += w * bf_hi(raw.x);
                acc[2] += w * bf_lo(raw.y); acc[3] += w * bf_hi(raw.y);
                acc[4] += w * bf_lo(raw.z); acc[5] += w * bf_hi(raw.z);
                acc[6] += w * bf_lo(raw.w); acc[7] += w * bf_hi(raw.w);
            }
        }
        const float4* ua = reinterpret_cast<const float4*>(u_acc + (size_t)b * D);
        const float4* va = reinterpret_cast<const float4*>(v_acc + (size_t)b * D);
        float4 u0 = ua[sub * 2], u1 = ua[sub * 2 + 1];
        float4 v0 = va[sub * 2], v1 = va[sub * 2 + 1];
        float partial =
            (u0.x + au[0]) * (v0.x + av[0]) + (u0.y + au[1]) * (v0.y + av[1]) +
            (u0.z + au[2]) * (v0.z + av[2]) + (u0.w + au[3]) * (v0.w + av[3]) +
            (u1.x + au[4]) * (v1.x + av[4]) + (u1.y + au[5]) * (v1.y + av[5]) +
            (u1.z + au[6]) * (v1.z + av[6]) + (u1.w + au[7]) * (v1.w + av[7]);
        partial += __shfl_xor(partial, 1, 64);
        partial += __shfl_xor(partial, 2, 64);
        partial += __shfl_xor(partial, 4, 64);
        if (sub == 0) {
            float g = partial * (1.0f / 16.0f);
            float y = labels[b];
            lb = fmaxf(g, 0.0f) - g * y + log1pf(expf(-fabsf(g)));
        }
    }
    lb += __shfl_xor(lb, 8, 64);
    lb += __shfl_xor(lb, 16, 64);
    lb += __shfl_xor(lb, 32, 64);
    __shared__ float sd[4];
    int wid = threadIdx.x >> 6;
    if ((threadIdx.x & 63) == 0) sd[wid] = lb;
    __syncthreads();
    if (threadIdx.x == 0)
        atomicAdd(out, (sd[0] + sd[1] + sd[2] + sd[3]) / (float)batch);
}

// ---------------------------------------------------------------------------
extern "C" void kernel_launch(void* const* d_in, const int* in_sizes, int n_in,
                              void* d_out, int out_size, void* d_ws, size_t ws_size,
                              hipStream_t stream) {
    const int* users = (const int*)d_in[0];
    const int* items = (const int*)d_in[1];
    const float* labels = (const float*)d_in[2];
    const int* edge_row = (const int*)d_in[3];
    const int* edge_col = (const int*)d_in[4];
    const float* edge_val = (const float*)d_in[5];
    const float* user_emb = (const float*)d_in[6];
    const float* item_emb = (const float*)d_in[7];

    const int batch = in_sizes[0];
    const int n_edges = in_sizes[3];
    const int n_user_rows = in_sizes[6] / D;   // 100001
    const int n_item_rows = in_sizes[7] / D;   // 50000
    const int n_total = n_user_rows + n_item_rows;
    const int nb = (n_total + RB - 1) / RB;          // 1172
    const int nblk = (n_edges + CHUNK - 1) / CHUNK;  // 489

    auto align256 = [](size_t x) { return (x + 255) & ~(size_t)255; };
    const size_t tblb_bytes = align256((size_t)n_total * D * 2);            // 19.2 MB bf16
    const size_t acc_bytes = align256((size_t)batch * D * sizeof(float));   // 2 MB
    const size_t off_bytes = align256((size_t)(n_total + 1) * sizeof(int)); // 600 KB
    const size_t pairs_bytes = align256((size_t)n_edges * sizeof(int2));    // 16 MB
    const size_t stage_bytes = align256((size_t)nblk * CHUNK * sizeof(int2)); // 16 MB
    const size_t loff_bytes = align256((size_t)nblk * (nb + 1) * sizeof(int)); // 2.3 MB
    const size_t coff_bytes = align256((size_t)(nb + 1) * sizeof(int));

    char* ws = (char*)d_ws;
    unsigned short* tbl  = (unsigned short*)ws;  ws += tblb_bytes;
    unsigned short* buf0 = (unsigned short*)ws;  ws += tblb_bytes;
    unsigned short* buf1 = (unsigned short*)ws;  ws += tblb_bytes;
    float* u_acc  = (float*)ws;                  ws += acc_bytes;
    float* v_acc  = (float*)ws;                  ws += acc_bytes;
    int*   offsets= (int*)ws;                    ws += off_bytes;
    int2*  pairs  = (int2*)ws;                   ws += pairs_bytes;
    // stage (16 MB) dead before spmm layer 1 writes buf0 -> alias (19.2 >= 16)
    int2*  stage  = (int2*)buf0;
    // loff/tot/coff dead before spmm layer 2 writes buf1 -> alias
    int*   loff   = (int*)buf1;
    int*   tot    = (int*)((char*)buf1 + loff_bytes);
    int*   coff   = (int*)((char*)buf1 + loff_bytes + coff_bytes);

    hipMemsetAsync(d_out, 0, sizeof(float) * out_size, stream);

    // ---- bf16 table conversion ----
    convert_kernel<<<2048, 256, 0, stream>>>(user_emb, item_emb, tbl, n_user_rows, n_total);

    // ---- CSR build: block-private sorted spans, no global atomics ----
    fill_sorted_kernel<<<nblk, 256, 0, stream>>>(edge_row, edge_col, edge_val,
                                                 stage, loff, n_edges, nb);
    const int wave_blocks = (nb + 3) / 4;  // 4 waves per 256-thread block
    col_sum_kernel<<<wave_blocks, 256, 0, stream>>>(loff, tot, nb, nblk);
    scan_tot_kernel<<<1, 256, 0, stream>>>(tot, coff, nb);
    bucket_finalize_kernel<<<nb, 256, 0, stream>>>(coff, loff, stage, offsets, pairs,
                                                   n_total, n_edges, nb, nblk);

    // ---- layer 0 batch gather ----
    const int ga_blocks = (batch * 16 + 255) / 256;
    gather_init_kernel<<<ga_blocks, 256, 0, stream>>>(users, items, user_emb, item_emb,
                                                      u_acc, v_acc, batch);

    // ---- layers 1,2 full propagation (bf16 gather, f32 accumulate) ----
    const int spmm_blocks = (int)(((size_t)n_total * 8 + 255) / 256);
    spmm_gather_kernel<<<spmm_blocks, 256, 0, stream>>>(offsets, pairs, tbl, buf0, n_total);
    gather_acc_kernel<<<ga_blocks, 256, 0, stream>>>(users, items, buf0,
                                                     u_acc, v_acc, batch, n_user_rows);
    spmm_gather_kernel<<<spmm_blocks, 256, 0, stream>>>(offsets, pairs, buf0, buf1, n_total);
    gather_acc_kernel<<<ga_blocks, 256, 0, stream>>>(users, items, buf1,
                                                     u_acc, v_acc, batch, n_user_rows);

    // ---- layer 3 computed ONLY at batch rows, fused with dot + BCE loss ----
    const int bl_blocks = (batch * 8 + 255) / 256;
    batch_l3_loss_kernel<<<bl_blocks, 256, 0, stream>>>(users, items, offsets, pairs,
                                                        buf1, u_acc, v_acc, labels,
                                                        (float*)d_out, batch, n_user_rows);
}

// Round 11
// 191.146 us; speedup vs baseline: 1.1315x; 1.1315x over previous
//
#include <hip/hip_runtime.h>
#include <hip/hip_bf16.h>

#define D 64
#define RB 128           // rows per coarse bucket (b = row>>7)
#define RB_SHIFT 7
#define COL_BITS 18      // n_total = 150001 < 2^18
#define COL_MASK 0x3FFFF
#define CHUNK 4096       // edges per partition block (489 blocks)
#define FT 512           // threads for hist/fill kernels

// bf16 helpers (round-to-nearest-even; bf16->f32 exact)
__device__ __forceinline__ unsigned f2bf(float f) {
    unsigned u = __float_as_uint(f);
    u += 0x7fff + ((u >> 16) & 1);
    return u >> 16;
}
__device__ __forceinline__ float bf_lo(unsigned w) {
    return __uint_as_float(w << 16);
}
__device__ __forceinline__ float bf_hi(unsigned w) {
    return __uint_as_float(w & 0xffff0000u);
}

// ---------------------------------------------------------------------------
// one-time: concat f32 tables -> bf16 table (n_total x 64)
__global__ void convert_kernel(const float* __restrict__ user_emb,
                               const float* __restrict__ item_emb,
                               unsigned short* __restrict__ tbl,
                               int n_user_rows, int n_total) {
    size_t t = (size_t)blockIdx.x * blockDim.x + threadIdx.x;
    size_t total4 = (size_t)n_total * (D / 4);
    size_t user4 = (size_t)n_user_rows * (D / 4);
    for (size_t i = t; i < total4; i += (size_t)gridDim.x * blockDim.x) {
        float4 v = (i < user4) ? reinterpret_cast<const float4*>(user_emb)[i]
                               : reinterpret_cast<const float4*>(item_emb)[i - user4];
        uint2 o;
        o.x = f2bf(v.x) | (f2bf(v.y) << 16);
        o.y = f2bf(v.z) | (f2bf(v.w) << 16);
        reinterpret_cast<uint2*>(tbl)[i] = o;
    }
}

// ---------------------------------------------------------------------------
// Pass A: per-chunk histogram over coarse buckets, BLOCK-MAJOR: hist[blk*nb + b]
__global__ void hist2_kernel(const int* __restrict__ row, int* __restrict__ hist,
                             int n_edges, int nb) {
    __shared__ int h[2048];
    for (int i = threadIdx.x; i < nb; i += FT) h[i] = 0;
    __syncthreads();
    int blk = blockIdx.x;
    int s = blk * CHUNK;
    int e = min(s + CHUNK, n_edges);
    for (int k = s + threadIdx.x; k < e; k += FT)
        atomicAdd(&h[row[k] >> RB_SHIFT], 1);
    __syncthreads();
    for (int i = threadIdx.x; i < nb; i += FT)
        hist[blk * nb + i] = h[i];   // coalesced row write
}

// Pass B1: tot[b] = sum over blk of hist[blk][b] — ONE WAVE per bucket
__global__ void col_sum_kernel(const int* __restrict__ hist, int* __restrict__ tot,
                               int nb, int nblk) {
    int w = (blockIdx.x * blockDim.x + threadIdx.x) >> 6;
    int lane = threadIdx.x & 63;
    if (w >= nb) return;
    int s = 0;
    for (int blk = lane; blk < nblk; blk += 64)
        s += hist[blk * nb + w];
    for (int off = 32; off > 0; off >>= 1)
        s += __shfl_down(s, off, 64);
    if (lane == 0) tot[w] = s;
}

// Pass B2: single-block exclusive scan of tot[0..nb) -> coff, coff[nb]=total
__global__ void scan_tot_kernel(const int* __restrict__ tot, int* __restrict__ coff,
                                int nb) {
    __shared__ int lds[256];
    int tid = threadIdx.x;
    int local[8];
    int sum = 0;
#pragma unroll
    for (int j = 0; j < 8; ++j) {
        int idx = tid * 8 + j;
        int v = (idx < nb) ? tot[idx] : 0;
        local[j] = sum;
        sum += v;
    }
    lds[tid] = sum;
    __syncthreads();
    for (int off = 1; off < 256; off <<= 1) {
        int v = (tid >= off) ? lds[tid - off] : 0;
        __syncthreads();
        lds[tid] += v;
        __syncthreads();
    }
    int prefix = (tid == 0) ? 0 : lds[tid - 1];
#pragma unroll
    for (int j = 0; j < 8; ++j) {
        int idx = tid * 8 + j;
        if (idx < nb) coff[idx] = prefix + local[j];
    }
    if (tid == 255) coff[nb] = lds[255];
}

// Pass B3: column exclusive scan — ONE WAVE per bucket
__global__ void col_scan_kernel(int* __restrict__ hist, const int* __restrict__ coff,
                                int nb, int nblk) {
    int w = (blockIdx.x * blockDim.x + threadIdx.x) >> 6;
    int lane = threadIdx.x & 63;
    if (w >= nb) return;
    int run = coff[w];
    for (int base = 0; base < nblk; base += 64) {
        int blk = base + lane;
        int v = (blk < nblk) ? hist[blk * nb + w] : 0;
        int inc = v;
#pragma unroll
        for (int off = 1; off < 64; off <<= 1) {
            int t = __shfl_up(inc, off, 64);
            if (lane >= off) inc += t;
        }
        if (blk < nblk) hist[blk * nb + w] = run + (inc - v);
        run += __shfl(inc, 63, 64);   // chunk total
    }
}

// Pass C: rank via block-private LDS cursors, write to exact positions
__global__ void fill_exact_kernel(const int* __restrict__ row, const int* __restrict__ col,
                                  const float* __restrict__ val, const int* __restrict__ hist,
                                  int2* __restrict__ stage, int n_edges, int nb) {
    __shared__ int cur[2048];
    int blk = blockIdx.x;
    for (int i = threadIdx.x; i < nb; i += FT)
        cur[i] = hist[blk * nb + i];   // coalesced row read
    __syncthreads();
    int s = blk * CHUNK;
    int e = min(s + CHUNK, n_edges);
    for (int k = s + threadIdx.x; k < e; k += FT) {
        int r = row[k];
        int b = r >> RB_SHIFT;
        int pos = atomicAdd(&cur[b], 1);
        stage[pos] = make_int2(col[k] | ((r & (RB - 1)) << COL_BITS), __float_as_int(val[k]));
    }
}

// per-bucket: sort edges by row within the CONTIGUOUS bucket span, emit offsets
__global__ void bucket_finalize_kernel(const int* __restrict__ coff,
                                       const int2* __restrict__ stage,
                                       int* __restrict__ offsets,
                                       int2* __restrict__ pairs,
                                       int n_total, int n_edges) {
    __shared__ int sc[RB];
    __shared__ int cur[RB];
    int b = blockIdx.x;
    int tid = threadIdx.x;
    int s = coff[b];
    int e_end = coff[b + 1];
    if (tid < RB) sc[tid] = 0;
    __syncthreads();
    for (int k = s + tid; k < e_end; k += blockDim.x)
        atomicAdd(&sc[stage[k].x >> COL_BITS], 1);
    __syncthreads();
    for (int off = 1; off < RB; off <<= 1) {
        int v = (tid < RB && tid >= off) ? sc[tid - off] : 0;
        __syncthreads();
        if (tid < RB) sc[tid] += v;
        __syncthreads();
    }
    if (tid < RB) {
        int excl = (tid == 0) ? 0 : sc[tid - 1];
        int r = b * RB + tid;
        if (r < n_total) offsets[r] = s + excl;
        cur[tid] = s + excl;
    }
    __syncthreads();
    for (int k = s + tid; k < e_end; k += blockDim.x) {
        int2 p = stage[k];
        int rl = p.x >> COL_BITS;
        int pos = atomicAdd(&cur[rl], 1);
        pairs[pos] = make_int2(p.x & COL_MASK, p.y);
    }
    if (b == 0 && tid == 0) offsets[n_total] = n_edges;
}

// ---------------------------------------------------------------------------
// gather spmm (bf16 src/dst, f32 accum): ONE 8-LANE GROUP PER ROW, edge loop
// 8/4/1 unroll cascade -> up to 8 independent row gathers in flight per group.
__global__ void spmm_gather_kernel(const int* __restrict__ offsets,
                                   const int2* __restrict__ pairs,
                                   const unsigned short* __restrict__ src,
                                   unsigned short* __restrict__ dst, int n_total) {
    int t = blockIdx.x * blockDim.x + threadIdx.x;
    int r = t >> 3;          // destination row
    int sub = t & 7;         // 16 B slice of the row
    if (r >= n_total) return;
    int start = offsets[r];
    int end = offsets[r + 1];
    const uint4* s4 = reinterpret_cast<const uint4*>(src);
    float a0 = 0.f, a1 = 0.f, a2 = 0.f, a3 = 0.f,
          a4 = 0.f, a5 = 0.f, a6 = 0.f, a7 = 0.f;
    int k = start;
    for (; k + 8 <= end; k += 8) {
        int2 p[8];
        uint4 rr[8];
#pragma unroll
        for (int j = 0; j < 8; ++j) p[j] = pairs[k + j];
#pragma unroll
        for (int j = 0; j < 8; ++j) rr[j] = s4[(size_t)p[j].x * 8 + sub];
#pragma unroll
        for (int j = 0; j < 8; ++j) {
            float w = __int_as_float(p[j].y);
            a0 += w * bf_lo(rr[j].x); a1 += w * bf_hi(rr[j].x);
            a2 += w * bf_lo(rr[j].y); a3 += w * bf_hi(rr[j].y);
            a4 += w * bf_lo(rr[j].z); a5 += w * bf_hi(rr[j].z);
            a6 += w * bf_lo(rr[j].w); a7 += w * bf_hi(rr[j].w);
        }
    }
    for (; k + 4 <= end; k += 4) {
        int2 p[4];
        uint4 rr[4];
#pragma unroll
        for (int j = 0; j < 4; ++j) p[j] = pairs[k + j];
#pragma unroll
        for (int j = 0; j < 4; ++j) rr[j] = s4[(size_t)p[j].x * 8 + sub];
#pragma unroll
        for (int j = 0; j < 4; ++j) {
            float w = __int_as_float(p[j].y);
            a0 += w * bf_lo(rr[j].x); a1 += w * bf_hi(rr[j].x);
            a2 += w * bf_lo(rr[j].y); a3 += w * bf_hi(rr[j].y);
            a4 += w * bf_lo(rr[j].z); a5 += w * bf_hi(rr[j].z);
            a6 += w * bf_lo(rr[j].w); a7 += w * bf_hi(rr[j].w);
        }
    }
    for (; k < end; ++k) {
        int2 p = pairs[k];
        float w = __int_as_float(p.y);
        uint4 raw = s4[(size_t)p.x * 8 + sub];
        a0 += w * bf_lo(raw.x); a1 += w * bf_hi(raw.x);
        a2 += w * bf_lo(raw.y); a3 += w * bf_hi(raw.y);
        a4 += w * bf_lo(raw.z); a5 += w * bf_hi(raw.z);
        a6 += w * bf_lo(raw.w); a7 += w * bf_hi(raw.w);
    }
    uint4 o;
    o.x = f2bf(a0) | (f2bf(a1) << 16);
    o.y = f2bf(a2) | (f2bf(a3) << 16);
    o.z = f2bf(a4) | (f2bf(a5) << 16);
    o.w = f2bf(a6) | (f2bf(a7) << 16);
    reinterpret_cast<uint4*>(dst + (size_t)r * D)[sub] = o;
}

// ---------------------------------------------------------------------------
// layer 0: write batch rows straight from the f32 source tables
__global__ void gather_init_kernel(const int* __restrict__ users,
                                   const int* __restrict__ items,
                                   const float* __restrict__ user_emb,
                                   const float* __restrict__ item_emb,
                                   float* __restrict__ u_acc,
                                   float* __restrict__ v_acc, int batch) {
    int t = blockIdx.x * blockDim.x + threadIdx.x;
    int b = t >> 4;
    int sub = t & 15;
    if (b >= batch) return;
    reinterpret_cast<float4*>(u_acc)[(size_t)b * 16 + sub] =
        reinterpret_cast<const float4*>(user_emb)[(size_t)users[b] * 16 + sub];
    reinterpret_cast<float4*>(v_acc)[(size_t)b * 16 + sub] =
        reinterpret_cast<const float4*>(item_emb)[(size_t)items[b] * 16 + sub];
}

// layers 1,2: accumulate batch rows from bf16 buf into f32 acc
__global__ void gather_acc_kernel(const int* __restrict__ users,
                                  const int* __restrict__ items,
                                  const unsigned short* __restrict__ buf,
                                  float* __restrict__ u_acc,
                                  float* __restrict__ v_acc,
                                  int batch, int n_user_rows) {
    int t = blockIdx.x * blockDim.x + threadIdx.x;
    int b = t >> 4;
    int sub = t & 15;
    if (b >= batch) return;
    uint2 ur = reinterpret_cast<const uint2*>(buf + (size_t)users[b] * D)[sub];
    uint2 vr = reinterpret_cast<const uint2*>(buf + (size_t)(n_user_rows + items[b]) * D)[sub];
    float4* up = reinterpret_cast<float4*>(u_acc) + (size_t)b * 16 + sub;
    float4* vp = reinterpret_cast<float4*>(v_acc) + (size_t)b * 16 + sub;
    float4 a = *up, c = *vp;
    a.x += bf_lo(ur.x); a.y += bf_hi(ur.x);
    a.z += bf_lo(ur.y); a.w += bf_hi(ur.y);
    c.x += bf_lo(vr.x); c.y += bf_hi(vr.x);
    c.z += bf_lo(vr.y); c.w += bf_hi(vr.y);
    *up = a;
    *vp = c;
}

// ---------------------------------------------------------------------------
// Fused final stage: per batch element, compute layer-3 ONLY for its user row
// and item row, add to the layer-0..2 accumulators, dot, BCE, reduce.
__global__ void batch_l3_loss_kernel(const int* __restrict__ users,
                                     const int* __restrict__ items,
                                     const int* __restrict__ offsets,
                                     const int2* __restrict__ pairs,
                                     const unsigned short* __restrict__ buf,
                                     const float* __restrict__ u_acc,
                                     const float* __restrict__ v_acc,
                                     const float* __restrict__ labels,
                                     float* __restrict__ out,
                                     int batch, int n_user_rows) {
    int t = blockIdx.x * blockDim.x + threadIdx.x;
    int b = t >> 3;
    int sub = t & 7;
    const uint4* s4 = reinterpret_cast<const uint4*>(buf);
    float lb = 0.0f;
    if (b < batch) {
        float au[8] = {0.f}, av[8] = {0.f};
        for (int side = 0; side < 2; ++side) {
            int row = (side == 0) ? users[b] : (n_user_rows + items[b]);
            float* acc = (side == 0) ? au : av;
            int k = offsets[row];
            int end = offsets[row + 1];
            for (; k + 2 <= end; k += 2) {
                int2 p0 = pairs[k + 0];
                int2 p1 = pairs[k + 1];
                uint4 r0 = s4[(size_t)p0.x * 8 + sub];
                uint4 r1 = s4[(size_t)p1.x * 8 + sub];
                float w0 = __int_as_float(p0.y), w1 = __int_as_float(p1.y);
                acc[0] += w0 * bf_lo(r0.x) + w1 * bf_lo(r1.x);
                acc[1] += w0 * bf_hi(r0.x) + w1 * bf_hi(r1.x);
                acc[2] += w0 * bf_lo(r0.y) + w1 * bf_lo(r1.y);
                acc[3] += w0 * bf_hi(r0.y) + w1 * bf_hi(r1.y);
                acc[4] += w0 * bf_lo(r0.z) + w1 * bf_lo(r1.z);
                acc[5] += w0 * bf_hi(r0.z) + w1 * bf_hi(r1.z);
                acc[6] += w0 * bf_lo(r0.w) + w1 * bf_lo(r1.w);
                acc[7] += w0 * bf_hi(r0.w) + w1 * bf_hi(r1.w);
            }
            for (; k < end; ++k) {
                int2 p = pairs[k];
                float w = __int_as_float(p.y);
                uint4 raw = s4[(size_t)p.x * 8 + sub];
                acc[0] += w * bf_lo(raw.x); acc[1] += w * bf_hi(raw.x);
                acc[2] += w * bf_lo(raw.y); acc[3] += w * bf_hi(raw.y);
                acc[4] += w * bf_lo(raw.z); acc[5] += w * bf_hi(raw.z);
                acc[6] += w * bf_lo(raw.w); acc[7] += w * bf_hi(raw.w);
            }
        }
        const float4* ua = reinterpret_cast<const float4*>(u_acc + (size_t)b * D);
        const float4* va = reinterpret_cast<const float4*>(v_acc + (size_t)b * D);
        float4 u0 = ua[sub * 2], u1 = ua[sub * 2 + 1];
        float4 v0 = va[sub * 2], v1 = va[sub * 2 + 1];
        float partial =
            (u0.x + au[0]) * (v0.x + av[0]) + (u0.y + au[1]) * (v0.y + av[1]) +
            (u0.z + au[2]) * (v0.z + av[2]) + (u0.w + au[3]) * (v0.w + av[3]) +
            (u1.x + au[4]) * (v1.x + av[4]) + (u1.y + au[5]) * (v1.y + av[5]) +
            (u1.z + au[6]) * (v1.z + av[6]) + (u1.w + au[7]) * (v1.w + av[7]);
        partial += __shfl_xor(partial, 1, 64);
        partial += __shfl_xor(partial, 2, 64);
        partial += __shfl_xor(partial, 4, 64);
        if (sub == 0) {
            float g = partial * (1.0f / 16.0f);
            float y = labels[b];
            lb = fmaxf(g, 0.0f) - g * y + log1pf(expf(-fabsf(g)));
        }
    }
    lb += __shfl_xor(lb, 8, 64);
    lb += __shfl_xor(lb, 16, 64);
    lb += __shfl_xor(lb, 32, 64);
    __shared__ float sd[4];
    int wid = threadIdx.x >> 6;
    if ((threadIdx.x & 63) == 0) sd[wid] = lb;
    __syncthreads();
    if (threadIdx.x == 0)
        atomicAdd(out, (sd[0] + sd[1] + sd[2] + sd[3]) / (float)batch);
}

// ---------------------------------------------------------------------------
extern "C" void kernel_launch(void* const* d_in, const int* in_sizes, int n_in,
                              void* d_out, int out_size, void* d_ws, size_t ws_size,
                              hipStream_t stream) {
    const int* users = (const int*)d_in[0];
    const int* items = (const int*)d_in[1];
    const float* labels = (const float*)d_in[2];
    const int* edge_row = (const int*)d_in[3];
    const int* edge_col = (const int*)d_in[4];
    const float* edge_val = (const float*)d_in[5];
    const float* user_emb = (const float*)d_in[6];
    const float* item_emb = (const float*)d_in[7];

    const int batch = in_sizes[0];
    const int n_edges = in_sizes[3];
    const int n_user_rows = in_sizes[6] / D;   // 100001
    const int n_item_rows = in_sizes[7] / D;   // 50000
    const int n_total = n_user_rows + n_item_rows;
    const int nb = (n_total + RB - 1) / RB;          // 1172
    const int nblk = (n_edges + CHUNK - 1) / CHUNK;  // 489
    const int L = nb * nblk;                          // 573,108

    auto align256 = [](size_t x) { return (x + 255) & ~(size_t)255; };
    const size_t tblb_bytes = align256((size_t)n_total * D * 2);            // 19.2 MB bf16
    const size_t acc_bytes = align256((size_t)batch * D * sizeof(float));   // 2 MB
    const size_t off_bytes = align256((size_t)(n_total + 1) * sizeof(int)); // 600 KB
    const size_t pairs_bytes = align256((size_t)n_edges * sizeof(int2));    // 16 MB
    const size_t hist_bytes = align256((size_t)L * sizeof(int));            // 2.3 MB
    const size_t coff_bytes = align256((size_t)(nb + 1) * sizeof(int));

    char* ws = (char*)d_ws;
    unsigned short* tbl  = (unsigned short*)ws;  ws += tblb_bytes;
    unsigned short* buf0 = (unsigned short*)ws;  ws += tblb_bytes;
    unsigned short* buf1 = (unsigned short*)ws;  ws += tblb_bytes;
    float* u_acc  = (float*)ws;                  ws += acc_bytes;
    float* v_acc  = (float*)ws;                  ws += acc_bytes;
    int*   offsets= (int*)ws;                    ws += off_bytes;
    int2*  pairs  = (int2*)ws;                   ws += pairs_bytes;
    // stage (16 MB) dead before spmm layer 1 writes buf0 -> alias
    int2*  stage  = (int2*)buf0;
    // hist/tot/coff dead before spmm layer 2 writes buf1 -> alias
    int*   hist   = (int*)buf1;
    int*   tot    = (int*)((char*)buf1 + hist_bytes);
    int*   coff   = (int*)((char*)buf1 + hist_bytes + coff_bytes);

    hipMemsetAsync(d_out, 0, sizeof(float) * out_size, stream);

    // ---- bf16 table conversion ----
    convert_kernel<<<2048, 256, 0, stream>>>(user_emb, item_emb, tbl, n_user_rows, n_total);

    // ---- CSR build: exact-offset two-level binning, no global atomics ----
    hist2_kernel<<<nblk, FT, 0, stream>>>(edge_row, hist, n_edges, nb);
    const int wave_blocks = (nb + 3) / 4;  // 4 waves per 256-thread block
    col_sum_kernel<<<wave_blocks, 256, 0, stream>>>(hist, tot, nb, nblk);
    scan_tot_kernel<<<1, 256, 0, stream>>>(tot, coff, nb);
    col_scan_kernel<<<wave_blocks, 256, 0, stream>>>(hist, coff, nb, nblk);
    fill_exact_kernel<<<nblk, FT, 0, stream>>>(edge_row, edge_col, edge_val,
                                               hist, stage, n_edges, nb);
    bucket_finalize_kernel<<<nb, 256, 0, stream>>>(coff, stage, offsets, pairs,
                                                   n_total, n_edges);

    // ---- layer 0 batch gather ----
    const int ga_blocks = (batch * 16 + 255) / 256;
    gather_init_kernel<<<ga_blocks, 256, 0, stream>>>(users, items, user_emb, item_emb,
                                                      u_acc, v_acc, batch);

    // ---- layers 1,2 full propagation (bf16 gather, f32 accumulate) ----
    const int spmm_blocks = (int)(((size_t)n_total * 8 + 255) / 256);
    spmm_gather_kernel<<<spmm_blocks, 256, 0, stream>>>(offsets, pairs, tbl, buf0, n_total);
    gather_acc_kernel<<<ga_blocks, 256, 0, stream>>>(users, items, buf0,
                                                     u_acc, v_acc, batch, n_user_rows);
    spmm_gather_kernel<<<spmm_blocks, 256, 0, stream>>>(offsets, pairs, buf0, buf1, n_total);
    gather_acc_kernel<<<ga_blocks, 256, 0, stream>>>(users, items, buf1,
                                                     u_acc, v_acc, batch, n_user_rows);

    // ---- layer 3 computed ONLY at batch rows, fused with dot + BCE loss ----
    const int bl_blocks = (batch * 8 + 255) / 256;
    batch_l3_loss_kernel<<<bl_blocks, 256, 0, stream>>>(users, items, offsets, pairs,
                                                        buf1, u_acc, v_acc, labels,
                                                        (float*)d_out, batch, n_user_rows);
}

// Round 12
// 185.477 us; speedup vs baseline: 1.1661x; 1.0306x over previous
//
#include <hip/hip_runtime.h>
#include <hip/hip_bf16.h>

#define D 64
#define RB 512           // rows per coarse bucket (b = row>>9)
#define RB_SHIFT 9
#define COL_BITS 18      // n_total = 150001 < 2^18; row_local in bits 18..26
#define COL_MASK 0x3FFFF
#define CHUNK 4096       // edges per partition block (489 blocks)
#define FT 512           // threads for hist/fill kernels

// bf16 helpers (round-to-nearest-even; bf16->f32 exact)
__device__ __forceinline__ unsigned f2bf(float f) {
    unsigned u = __float_as_uint(f);
    u += 0x7fff + ((u >> 16) & 1);
    return u >> 16;
}
__device__ __forceinline__ float bf_lo(unsigned w) {
    return __uint_as_float(w << 16);
}
__device__ __forceinline__ float bf_hi(unsigned w) {
    return __uint_as_float(w & 0xffff0000u);
}

// ---------------------------------------------------------------------------
// one-time: concat f32 tables -> bf16 table (n_total x 64)
__global__ void convert_kernel(const float* __restrict__ user_emb,
                               const float* __restrict__ item_emb,
                               unsigned short* __restrict__ tbl,
                               int n_user_rows, int n_total) {
    size_t t = (size_t)blockIdx.x * blockDim.x + threadIdx.x;
    size_t total4 = (size_t)n_total * (D / 4);
    size_t user4 = (size_t)n_user_rows * (D / 4);
    for (size_t i = t; i < total4; i += (size_t)gridDim.x * blockDim.x) {
        float4 v = (i < user4) ? reinterpret_cast<const float4*>(user_emb)[i]
                               : reinterpret_cast<const float4*>(item_emb)[i - user4];
        uint2 o;
        o.x = f2bf(v.x) | (f2bf(v.y) << 16);
        o.y = f2bf(v.z) | (f2bf(v.w) << 16);
        reinterpret_cast<uint2*>(tbl)[i] = o;
    }
}

// ---------------------------------------------------------------------------
// Pass A: per-chunk histogram over coarse buckets, BLOCK-MAJOR: hist[blk*nb + b]
__global__ void hist2_kernel(const int* __restrict__ row, int* __restrict__ hist,
                             int n_edges, int nb) {
    __shared__ int h[RB];   // nb <= 293 < 512
    for (int i = threadIdx.x; i < nb; i += FT) h[i] = 0;
    __syncthreads();
    int blk = blockIdx.x;
    int s = blk * CHUNK;
    int e = min(s + CHUNK, n_edges);
    for (int k = s + threadIdx.x; k < e; k += FT)
        atomicAdd(&h[row[k] >> RB_SHIFT], 1);
    __syncthreads();
    for (int i = threadIdx.x; i < nb; i += FT)
        hist[blk * nb + i] = h[i];   // coalesced row write
}

// Pass B1: tot[b] = sum over blk of hist[blk][b] — ONE WAVE per bucket
__global__ void col_sum_kernel(const int* __restrict__ hist, int* __restrict__ tot,
                               int nb, int nblk) {
    int w = (blockIdx.x * blockDim.x + threadIdx.x) >> 6;
    int lane = threadIdx.x & 63;
    if (w >= nb) return;
    int s = 0;
    for (int blk = lane; blk < nblk; blk += 64)
        s += hist[blk * nb + w];
    for (int off = 32; off > 0; off >>= 1)
        s += __shfl_down(s, off, 64);
    if (lane == 0) tot[w] = s;
}

// Pass B2: single-block exclusive scan of tot[0..nb) -> coff, coff[nb]=total
__global__ void scan_tot_kernel(const int* __restrict__ tot, int* __restrict__ coff,
                                int nb) {
    __shared__ int lds[256];
    int tid = threadIdx.x;
    int local[8];
    int sum = 0;
#pragma unroll
    for (int j = 0; j < 8; ++j) {
        int idx = tid * 8 + j;
        int v = (idx < nb) ? tot[idx] : 0;
        local[j] = sum;
        sum += v;
    }
    lds[tid] = sum;
    __syncthreads();
    for (int off = 1; off < 256; off <<= 1) {
        int v = (tid >= off) ? lds[tid - off] : 0;
        __syncthreads();
        lds[tid] += v;
        __syncthreads();
    }
    int prefix = (tid == 0) ? 0 : lds[tid - 1];
#pragma unroll
    for (int j = 0; j < 8; ++j) {
        int idx = tid * 8 + j;
        if (idx < nb) coff[idx] = prefix + local[j];
    }
    if (tid == 255) coff[nb] = lds[255];
}

// Pass B3: column exclusive scan — ONE WAVE per bucket
__global__ void col_scan_kernel(int* __restrict__ hist, const int* __restrict__ coff,
                                int nb, int nblk) {
    int w = (blockIdx.x * blockDim.x + threadIdx.x) >> 6;
    int lane = threadIdx.x & 63;
    if (w >= nb) return;
    int run = coff[w];
    for (int base = 0; base < nblk; base += 64) {
        int blk = base + lane;
        int v = (blk < nblk) ? hist[blk * nb + w] : 0;
        int inc = v;
#pragma unroll
        for (int off = 1; off < 64; off <<= 1) {
            int t = __shfl_up(inc, off, 64);
            if (lane >= off) inc += t;
        }
        if (blk < nblk) hist[blk * nb + w] = run + (inc - v);
        run += __shfl(inc, 63, 64);   // chunk total
    }
}

// Pass C: rank via block-private LDS cursors, write to exact positions
__global__ void fill_exact_kernel(const int* __restrict__ row, const int* __restrict__ col,
                                  const float* __restrict__ val, const int* __restrict__ hist,
                                  int2* __restrict__ stage, int n_edges, int nb) {
    __shared__ int cur[RB];
    int blk = blockIdx.x;
    for (int i = threadIdx.x; i < nb; i += FT)
        cur[i] = hist[blk * nb + i];   // coalesced row read
    __syncthreads();
    int s = blk * CHUNK;
    int e = min(s + CHUNK, n_edges);
    for (int k = s + threadIdx.x; k < e; k += FT) {
        int r = row[k];
        int b = r >> RB_SHIFT;
        int pos = atomicAdd(&cur[b], 1);
        stage[pos] = make_int2(col[k] | ((r & (RB - 1)) << COL_BITS), __float_as_int(val[k]));
    }
}

// per-bucket (512 rows): sort edges by row within the CONTIGUOUS bucket span,
// emit row-level offsets. 512 threads, sc/cur[512].
__global__ void bucket_finalize_kernel(const int* __restrict__ coff,
                                       const int2* __restrict__ stage,
                                       int* __restrict__ offsets,
                                       int2* __restrict__ pairs,
                                       int n_total, int n_edges) {
    __shared__ int sc[RB];
    __shared__ int cur[RB];
    int b = blockIdx.x;
    int tid = threadIdx.x;
    int s = coff[b];
    int e_end = coff[b + 1];
    sc[tid] = 0;
    __syncthreads();
    for (int k = s + tid; k < e_end; k += blockDim.x)
        atomicAdd(&sc[stage[k].x >> COL_BITS], 1);
    __syncthreads();
    // inclusive scan of 512 counters (Hillis-Steele)
    for (int off = 1; off < RB; off <<= 1) {
        int v = (tid >= off) ? sc[tid - off] : 0;
        __syncthreads();
        sc[tid] += v;
        __syncthreads();
    }
    {
        int excl = (tid == 0) ? 0 : sc[tid - 1];
        int r = b * RB + tid;
        if (r < n_total) offsets[r] = s + excl;
        cur[tid] = s + excl;
    }
    __syncthreads();
    for (int k = s + tid; k < e_end; k += blockDim.x) {
        int2 p = stage[k];
        int rl = p.x >> COL_BITS;
        int pos = atomicAdd(&cur[rl], 1);
        pairs[pos] = make_int2(p.x & COL_MASK, p.y);
    }
    if (b == 0 && tid == 0) offsets[n_total] = n_edges;
}

// ---------------------------------------------------------------------------
// gather spmm (bf16 src/dst, f32 accum): ONE 8-LANE GROUP PER ROW, edge loop
// 8/4/1 unroll cascade -> up to 8 independent row gathers in flight per group.
__global__ void spmm_gather_kernel(const int* __restrict__ offsets,
                                   const int2* __restrict__ pairs,
                                   const unsigned short* __restrict__ src,
                                   unsigned short* __restrict__ dst, int n_total) {
    int t = blockIdx.x * blockDim.x + threadIdx.x;
    int r = t >> 3;          // destination row
    int sub = t & 7;         // 16 B slice of the row
    if (r >= n_total) return;
    int start = offsets[r];
    int end = offsets[r + 1];
    const uint4* s4 = reinterpret_cast<const uint4*>(src);
    float a0 = 0.f, a1 = 0.f, a2 = 0.f, a3 = 0.f,
          a4 = 0.f, a5 = 0.f, a6 = 0.f, a7 = 0.f;
    int k = start;
    for (; k + 8 <= end; k += 8) {
        int2 p[8];
        uint4 rr[8];
#pragma unroll
        for (int j = 0; j < 8; ++j) p[j] = pairs[k + j];
#pragma unroll
        for (int j = 0; j < 8; ++j) rr[j] = s4[(size_t)p[j].x * 8 + sub];
#pragma unroll
        for (int j = 0; j < 8; ++j) {
            float w = __int_as_float(p[j].y);
            a0 += w * bf_lo(rr[j].x); a1 += w * bf_hi(rr[j].x);
            a2 += w * bf_lo(rr[j].y); a3 += w * bf_hi(rr[j].y);
            a4 += w * bf_lo(rr[j].z); a5 += w * bf_hi(rr[j].z);
            a6 += w * bf_lo(rr[j].w); a7 += w * bf_hi(rr[j].w);
        }
    }
    for (; k + 4 <= end; k += 4) {
        int2 p[4];
        uint4 rr[4];
#pragma unroll
        for (int j = 0; j < 4; ++j) p[j] = pairs[k + j];
#pragma unroll
        for (int j = 0; j < 4; ++j) rr[j] = s4[(size_t)p[j].x * 8 + sub];
#pragma unroll
        for (int j = 0; j < 4; ++j) {
            float w = __int_as_float(p[j].y);
            a0 += w * bf_lo(rr[j].x); a1 += w * bf_hi(rr[j].x);
            a2 += w * bf_lo(rr[j].y); a3 += w * bf_hi(rr[j].y);
            a4 += w * bf_lo(rr[j].z); a5 += w * bf_hi(rr[j].z);
            a6 += w * bf_lo(rr[j].w); a7 += w * bf_hi(rr[j].w);
        }
    }
    for (; k < end; ++k) {
        int2 p = pairs[k];
        float w = __int_as_float(p.y);
        uint4 raw = s4[(size_t)p.x * 8 + sub];
        a0 += w * bf_lo(raw.x); a1 += w * bf_hi(raw.x);
        a2 += w * bf_lo(raw.y); a3 += w * bf_hi(raw.y);
        a4 += w * bf_lo(raw.z); a5 += w * bf_hi(raw.z);
        a6 += w * bf_lo(raw.w); a7 += w * bf_hi(raw.w);
    }
    uint4 o;
    o.x = f2bf(a0) | (f2bf(a1) << 16);
    o.y = f2bf(a2) | (f2bf(a3) << 16);
    o.z = f2bf(a4) | (f2bf(a5) << 16);
    o.w = f2bf(a6) | (f2bf(a7) << 16);
    reinterpret_cast<uint4*>(dst + (size_t)r * D)[sub] = o;
}

// ---------------------------------------------------------------------------
// layer 0: write batch rows straight from the f32 source tables
__global__ void gather_init_kernel(const int* __restrict__ users,
                                   const int* __restrict__ items,
                                   const float* __restrict__ user_emb,
                                   const float* __restrict__ item_emb,
                                   float* __restrict__ u_acc,
                                   float* __restrict__ v_acc, int batch) {
    int t = blockIdx.x * blockDim.x + threadIdx.x;
    int b = t >> 4;
    int sub = t & 15;
    if (b >= batch) return;
    reinterpret_cast<float4*>(u_acc)[(size_t)b * 16 + sub] =
        reinterpret_cast<const float4*>(user_emb)[(size_t)users[b] * 16 + sub];
    reinterpret_cast<float4*>(v_acc)[(size_t)b * 16 + sub] =
        reinterpret_cast<const float4*>(item_emb)[(size_t)items[b] * 16 + sub];
}

// layers 1,2: accumulate batch rows from bf16 buf into f32 acc
__global__ void gather_acc_kernel(const int* __restrict__ users,
                                  const int* __restrict__ items,
                                  const unsigned short* __restrict__ buf,
                                  float* __restrict__ u_acc,
                                  float* __restrict__ v_acc,
                                  int batch, int n_user_rows) {
    int t = blockIdx.x * blockDim.x + threadIdx.x;
    int b = t >> 4;
    int sub = t & 15;
    if (b >= batch) return;
    uint2 ur = reinterpret_cast<const uint2*>(buf + (size_t)users[b] * D)[sub];
    uint2 vr = reinterpret_cast<const uint2*>(buf + (size_t)(n_user_rows + items[b]) * D)[sub];
    float4* up = reinterpret_cast<float4*>(u_acc) + (size_t)b * 16 + sub;
    float4* vp = reinterpret_cast<float4*>(v_acc) + (size_t)b * 16 + sub;
    float4 a = *up, c = *vp;
    a.x += bf_lo(ur.x); a.y += bf_hi(ur.x);
    a.z += bf_lo(ur.y); a.w += bf_hi(ur.y);
    c.x += bf_lo(vr.x); c.y += bf_hi(vr.x);
    c.z += bf_lo(vr.y); c.w += bf_hi(vr.y);
    *up = a;
    *vp = c;
}

// ---------------------------------------------------------------------------
// Fused final stage: per batch element, compute layer-3 ONLY for its user row
// and item row, add to the layer-0..2 accumulators, dot, BCE, reduce.
__global__ void batch_l3_loss_kernel(const int* __restrict__ users,
                                     const int* __restrict__ items,
                                     const int* __restrict__ offsets,
                                     const int2* __restrict__ pairs,
                                     const unsigned short* __restrict__ buf,
                                     const float* __restrict__ u_acc,
                                     const float* __restrict__ v_acc,
                                     const float* __restrict__ labels,
                                     float* __restrict__ out,
                                     int batch, int n_user_rows) {
    int t = blockIdx.x * blockDim.x + threadIdx.x;
    int b = t >> 3;
    int sub = t & 7;
    const uint4* s4 = reinterpret_cast<const uint4*>(buf);
    float lb = 0.0f;
    if (b < batch) {
        float au[8] = {0.f}, av[8] = {0.f};
        for (int side = 0; side < 2; ++side) {
            int row = (side == 0) ? users[b] : (n_user_rows + items[b]);
            float* acc = (side == 0) ? au : av;
            int k = offsets[row];
            int end = offsets[row + 1];
            for (; k + 2 <= end; k += 2) {
                int2 p0 = pairs[k + 0];
                int2 p1 = pairs[k + 1];
                uint4 r0 = s4[(size_t)p0.x * 8 + sub];
                uint4 r1 = s4[(size_t)p1.x * 8 + sub];
                float w0 = __int_as_float(p0.y), w1 = __int_as_float(p1.y);
                acc[0] += w0 * bf_lo(r0.x) + w1 * bf_lo(r1.x);
                acc[1] += w0 * bf_hi(r0.x) + w1 * bf_hi(r1.x);
                acc[2] += w0 * bf_lo(r0.y) + w1 * bf_lo(r1.y);
                acc[3] += w0 * bf_hi(r0.y) + w1 * bf_hi(r1.y);
                acc[4] += w0 * bf_lo(r0.z) + w1 * bf_lo(r1.z);
                acc[5] += w0 * bf_hi(r0.z) + w1 * bf_hi(r1.z);
                acc[6] += w0 * bf_lo(r0.w) + w1 * bf_lo(r1.w);
                acc[7] += w0 * bf_hi(r0.w) + w1 * bf_hi(r1.w);
            }
            for (; k < end; ++k) {
                int2 p = pairs[k];
                float w = __int_as_float(p.y);
                uint4 raw = s4[(size_t)p.x * 8 + sub];
                acc[0] += w * bf_lo(raw.x); acc[1] += w * bf_hi(raw.x);
                acc[2] += w * bf_lo(raw.y); acc[3] += w * bf_hi(raw.y);
                acc[4] += w * bf_lo(raw.z); acc[5] += w * bf_hi(raw.z);
                acc[6] += w * bf_lo(raw.w); acc[7] += w * bf_hi(raw.w);
            }
        }
        const float4* ua = reinterpret_cast<const float4*>(u_acc + (size_t)b * D);
        const float4* va = reinterpret_cast<const float4*>(v_acc + (size_t)b * D);
        float4 u0 = ua[sub * 2], u1 = ua[sub * 2 + 1];
        float4 v0 = va[sub * 2], v1 = va[sub * 2 + 1];
        float partial =
            (u0.x + au[0]) * (v0.x + av[0]) + (u0.y + au[1]) * (v0.y + av[1]) +
            (u0.z + au[2]) * (v0.z + av[2]) + (u0.w + au[3]) * (v0.w + av[3]) +
            (u1.x + au[4]) * (v1.x + av[4]) + (u1.y + au[5]) * (v1.y + av[5]) +
            (u1.z + au[6]) * (v1.z + av[6]) + (u1.w + au[7]) * (v1.w + av[7]);
        partial += __shfl_xor(partial, 1, 64);
        partial += __shfl_xor(partial, 2, 64);
        partial += __shfl_xor(partial, 4, 64);
        if (sub == 0) {
            float g = partial * (1.0f / 16.0f);
            float y = labels[b];
            lb = fmaxf(g, 0.0f) - g * y + log1pf(expf(-fabsf(g)));
        }
    }
    lb += __shfl_xor(lb, 8, 64);
    lb += __shfl_xor(lb, 16, 64);
    lb += __shfl_xor(lb, 32, 64);
    __shared__ float sd[4];
    int wid = threadIdx.x >> 6;
    if ((threadIdx.x & 63) == 0) sd[wid] = lb;
    __syncthreads();
    if (threadIdx.x == 0)
        atomicAdd(out, (sd[0] + sd[1] + sd[2] + sd[3]) / (float)batch);
}

// ---------------------------------------------------------------------------
extern "C" void kernel_launch(void* const* d_in, const int* in_sizes, int n_in,
                              void* d_out, int out_size, void* d_ws, size_t ws_size,
                              hipStream_t stream) {
    const int* users = (const int*)d_in[0];
    const int* items = (const int*)d_in[1];
    const float* labels = (const float*)d_in[2];
    const int* edge_row = (const int*)d_in[3];
    const int* edge_col = (const int*)d_in[4];
    const float* edge_val = (const float*)d_in[5];
    const float* user_emb = (const float*)d_in[6];
    const float* item_emb = (const float*)d_in[7];

    const int batch = in_sizes[0];
    const int n_edges = in_sizes[3];
    const int n_user_rows = in_sizes[6] / D;   // 100001
    const int n_item_rows = in_sizes[7] / D;   // 50000
    const int n_total = n_user_rows + n_item_rows;
    const int nb = (n_total + RB - 1) / RB;          // 293
    const int nblk = (n_edges + CHUNK - 1) / CHUNK;  // 489
    const int L = nb * nblk;                          // 143,277

    auto align256 = [](size_t x) { return (x + 255) & ~(size_t)255; };
    const size_t tblb_bytes = align256((size_t)n_total * D * 2);            // 19.2 MB bf16
    const size_t acc_bytes = align256((size_t)batch * D * sizeof(float));   // 2 MB
    const size_t off_bytes = align256((size_t)(n_total + 1) * sizeof(int)); // 600 KB
    const size_t pairs_bytes = align256((size_t)n_edges * sizeof(int2));    // 16 MB
    const size_t hist_bytes = align256((size_t)L * sizeof(int));            // 573 KB
    const size_t coff_bytes = align256((size_t)(nb + 1) * sizeof(int));

    char* ws = (char*)d_ws;
    unsigned short* tbl  = (unsigned short*)ws;  ws += tblb_bytes;
    unsigned short* buf0 = (unsigned short*)ws;  ws += tblb_bytes;
    unsigned short* buf1 = (unsigned short*)ws;  ws += tblb_bytes;
    float* u_acc  = (float*)ws;                  ws += acc_bytes;
    float* v_acc  = (float*)ws;                  ws += acc_bytes;
    int*   offsets= (int*)ws;                    ws += off_bytes;
    int2*  pairs  = (int2*)ws;                   ws += pairs_bytes;
    // stage (16 MB) dead before spmm layer 1 writes buf0 -> alias
    int2*  stage  = (int2*)buf0;
    // hist/tot/coff dead before spmm layer 2 writes buf1 -> alias
    int*   hist   = (int*)buf1;
    int*   tot    = (int*)((char*)buf1 + hist_bytes);
    int*   coff   = (int*)((char*)buf1 + hist_bytes + coff_bytes);

    hipMemsetAsync(d_out, 0, sizeof(float) * out_size, stream);

    // ---- bf16 table conversion ----
    convert_kernel<<<2048, 256, 0, stream>>>(user_emb, item_emb, tbl, n_user_rows, n_total);

    // ---- CSR build: exact-offset two-level binning, no global atomics ----
    hist2_kernel<<<nblk, FT, 0, stream>>>(edge_row, hist, n_edges, nb);
    const int wave_blocks = (nb + 3) / 4;  // 4 waves per 256-thread block
    col_sum_kernel<<<wave_blocks, 256, 0, stream>>>(hist, tot, nb, nblk);
    scan_tot_kernel<<<1, 256, 0, stream>>>(tot, coff, nb);
    col_scan_kernel<<<wave_blocks, 256, 0, stream>>>(hist, coff, nb, nblk);
    fill_exact_kernel<<<nblk, FT, 0, stream>>>(edge_row, edge_col, edge_val,
                                               hist, stage, n_edges, nb);
    bucket_finalize_kernel<<<nb, RB, 0, stream>>>(coff, stage, offsets, pairs,
                                                  n_total, n_edges);

    // ---- layer 0 batch gather ----
    const int ga_blocks = (batch * 16 + 255) / 256;
    gather_init_kernel<<<ga_blocks, 256, 0, stream>>>(users, items, user_emb, item_emb,
                                                      u_acc, v_acc, batch);

    // ---- layers 1,2 full propagation (bf16 gather, f32 accumulate) ----
    const int spmm_blocks = (int)(((size_t)n_total * 8 + 255) / 256);
    spmm_gather_kernel<<<spmm_blocks, 256, 0, stream>>>(offsets, pairs, tbl, buf0, n_total);
    gather_acc_kernel<<<ga_blocks, 256, 0, stream>>>(users, items, buf0,
                                                     u_acc, v_acc, batch, n_user_rows);
    spmm_gather_kernel<<<spmm_blocks, 256, 0, stream>>>(offsets, pairs, buf0, buf1, n_total);
    gather_acc_kernel<<<ga_blocks, 256, 0, stream>>>(users, items, buf1,
                                                     u_acc, v_acc, batch, n_user_rows);

    // ---- layer 3 computed ONLY at batch rows, fused with dot + BCE loss ----
    const int bl_blocks = (batch * 8 + 255) / 256;
    batch_l3_loss_kernel<<<bl_blocks, 256, 0, stream>>>(users, items, offsets, pairs,
                                                        buf1, u_acc, v_acc, labels,
                                                        (float*)d_out, batch, n_user_rows);
}

// Round 13
// 182.767 us; speedup vs baseline: 1.1834x; 1.0148x over previous
//
#include <hip/hip_runtime.h>
#include <hip/hip_bf16.h>

#define D 64
#define RB 512           // rows per coarse bucket (b = row>>9)
#define RB_SHIFT 9
#define COL_BITS 18      // n_total = 150001 < 2^18; row_local in bits 18..26
#define COL_MASK 0x3FFFF
#define CHUNK 4096       // edges per partition block (489 blocks)
#define FT 512           // threads for hist/fill kernels

// bf16 helpers (round-to-nearest-even; bf16->f32 exact)
__device__ __forceinline__ unsigned f2bf(float f) {
    unsigned u = __float_as_uint(f);
    u += 0x7fff + ((u >> 16) & 1);
    return u >> 16;
}
__device__ __forceinline__ float bf_lo(unsigned w) {
    return __uint_as_float(w << 16);
}
__device__ __forceinline__ float bf_hi(unsigned w) {
    return __uint_as_float(w & 0xffff0000u);
}

// ---------------------------------------------------------------------------
// one-time: concat f32 tables -> bf16 table (n_total x 64)
__global__ void convert_kernel(const float* __restrict__ user_emb,
                               const float* __restrict__ item_emb,
                               unsigned short* __restrict__ tbl,
                               int n_user_rows, int n_total) {
    size_t t = (size_t)blockIdx.x * blockDim.x + threadIdx.x;
    size_t total4 = (size_t)n_total * (D / 4);
    size_t user4 = (size_t)n_user_rows * (D / 4);
    for (size_t i = t; i < total4; i += (size_t)gridDim.x * blockDim.x) {
        float4 v = (i < user4) ? reinterpret_cast<const float4*>(user_emb)[i]
                               : reinterpret_cast<const float4*>(item_emb)[i - user4];
        uint2 o;
        o.x = f2bf(v.x) | (f2bf(v.y) << 16);
        o.y = f2bf(v.z) | (f2bf(v.w) << 16);
        reinterpret_cast<uint2*>(tbl)[i] = o;
    }
}

// ---------------------------------------------------------------------------
// Pass A: per-chunk histogram over coarse buckets, BLOCK-MAJOR: hist[blk*nb + b]
__global__ void hist2_kernel(const int* __restrict__ row, int* __restrict__ hist,
                             int n_edges, int nb) {
    __shared__ int h[RB];   // nb <= 293 < 512
    for (int i = threadIdx.x; i < nb; i += FT) h[i] = 0;
    __syncthreads();
    int blk = blockIdx.x;
    int s = blk * CHUNK;
    int e = min(s + CHUNK, n_edges);
    for (int k = s + threadIdx.x; k < e; k += FT)
        atomicAdd(&h[row[k] >> RB_SHIFT], 1);
    __syncthreads();
    for (int i = threadIdx.x; i < nb; i += FT)
        hist[blk * nb + i] = h[i];   // coalesced row write
}

// Pass B1: tot[b] = sum over blk of hist[blk][b] — ONE WAVE per bucket
__global__ void col_sum_kernel(const int* __restrict__ hist, int* __restrict__ tot,
                               int nb, int nblk) {
    int w = (blockIdx.x * blockDim.x + threadIdx.x) >> 6;
    int lane = threadIdx.x & 63;
    if (w >= nb) return;
    int s = 0;
    for (int blk = lane; blk < nblk; blk += 64)
        s += hist[blk * nb + w];
    for (int off = 32; off > 0; off >>= 1)
        s += __shfl_down(s, off, 64);
    if (lane == 0) tot[w] = s;
}

// Pass B2: single-block exclusive scan of tot[0..nb) -> coff, coff[nb]=total
__global__ void scan_tot_kernel(const int* __restrict__ tot, int* __restrict__ coff,
                                int nb) {
    __shared__ int lds[256];
    int tid = threadIdx.x;
    int local[8];
    int sum = 0;
#pragma unroll
    for (int j = 0; j < 8; ++j) {
        int idx = tid * 8 + j;
        int v = (idx < nb) ? tot[idx] : 0;
        local[j] = sum;
        sum += v;
    }
    lds[tid] = sum;
    __syncthreads();
    for (int off = 1; off < 256; off <<= 1) {
        int v = (tid >= off) ? lds[tid - off] : 0;
        __syncthreads();
        lds[tid] += v;
        __syncthreads();
    }
    int prefix = (tid == 0) ? 0 : lds[tid - 1];
#pragma unroll
    for (int j = 0; j < 8; ++j) {
        int idx = tid * 8 + j;
        if (idx < nb) coff[idx] = prefix + local[j];
    }
    if (tid == 255) coff[nb] = lds[255];
}

// Pass B3: column exclusive scan — ONE WAVE per bucket
__global__ void col_scan_kernel(int* __restrict__ hist, const int* __restrict__ coff,
                                int nb, int nblk) {
    int w = (blockIdx.x * blockDim.x + threadIdx.x) >> 6;
    int lane = threadIdx.x & 63;
    if (w >= nb) return;
    int run = coff[w];
    for (int base = 0; base < nblk; base += 64) {
        int blk = base + lane;
        int v = (blk < nblk) ? hist[blk * nb + w] : 0;
        int inc = v;
#pragma unroll
        for (int off = 1; off < 64; off <<= 1) {
            int t = __shfl_up(inc, off, 64);
            if (lane >= off) inc += t;
        }
        if (blk < nblk) hist[blk * nb + w] = run + (inc - v);
        run += __shfl(inc, 63, 64);   // chunk total
    }
}

// Pass C: rank via block-private LDS cursors, write to exact positions
__global__ void fill_exact_kernel(const int* __restrict__ row, const int* __restrict__ col,
                                  const float* __restrict__ val, const int* __restrict__ hist,
                                  int2* __restrict__ stage, int n_edges, int nb) {
    __shared__ int cur[RB];
    int blk = blockIdx.x;
    for (int i = threadIdx.x; i < nb; i += FT)
        cur[i] = hist[blk * nb + i];   // coalesced row read
    __syncthreads();
    int s = blk * CHUNK;
    int e = min(s + CHUNK, n_edges);
    for (int k = s + threadIdx.x; k < e; k += FT) {
        int r = row[k];
        int b = r >> RB_SHIFT;
        int pos = atomicAdd(&cur[b], 1);
        stage[pos] = make_int2(col[k] | ((r & (RB - 1)) << COL_BITS), __float_as_int(val[k]));
    }
}

// Pass D1: per-bucket row histogram -> rowcnt (global) + PADDED bucket totals
// (each row's edge count rounded up to a multiple of 4 for tail-free spmm).
__global__ void bucket_count_kernel(const int* __restrict__ coff,
                                    const int2* __restrict__ stage,
                                    int* __restrict__ rowcnt,
                                    int* __restrict__ tot2) {
    __shared__ int sc[RB];
    __shared__ int wsum[RB / 64];
    int b = blockIdx.x;
    int tid = threadIdx.x;
    int s = coff[b], e = coff[b + 1];
    sc[tid] = 0;
    __syncthreads();
    for (int k = s + tid; k < e; k += RB)
        atomicAdd(&sc[stage[k].x >> COL_BITS], 1);
    __syncthreads();
    int cnt = sc[tid];
    rowcnt[b * RB + tid] = cnt;
    int pad = (cnt + 3) & ~3;
    for (int off = 32; off > 0; off >>= 1)
        pad += __shfl_down(pad, off, 64);
    if ((tid & 63) == 0) wsum[tid >> 6] = pad;
    __syncthreads();
    if (tid == 0) {
        int t = 0;
#pragma unroll
        for (int i = 0; i < RB / 64; ++i) t += wsum[i];
        tot2[b] = t;
    }
}

// Pass D2: per-bucket scatter into padded row slots; pad with (col=0, w=0).
__global__ void bucket_scatter_kernel(const int* __restrict__ coff,
                                      const int* __restrict__ coff2,
                                      const int* __restrict__ rowcnt,
                                      const int2* __restrict__ stage,
                                      int* __restrict__ offsets,
                                      int2* __restrict__ pairs,
                                      int n_total, int nb) {
    __shared__ int sc[RB];
    __shared__ int cur[RB];
    int b = blockIdx.x;
    int tid = threadIdx.x;
    int s = coff[b], e = coff[b + 1];
    int cnt = rowcnt[b * RB + tid];
    int pad = (cnt + 3) & ~3;
    sc[tid] = pad;
    __syncthreads();
    for (int off = 1; off < RB; off <<= 1) {
        int v = (tid >= off) ? sc[tid - off] : 0;
        __syncthreads();
        sc[tid] += v;
        __syncthreads();
    }
    int start = coff2[b] + sc[tid] - pad;   // exclusive padded prefix
    int r = b * RB + tid;
    if (r < n_total) offsets[r] = start;
    cur[tid] = start;
    // fill this row's pad slots (disjoint from real slots)
    for (int q = start + cnt; q < start + pad; ++q)
        pairs[q] = make_int2(0, 0);   // col 0, weight 0.0f
    __syncthreads();
    for (int k = s + tid; k < e; k += RB) {
        int2 p = stage[k];
        int rl = p.x >> COL_BITS;
        int pos = atomicAdd(&cur[rl], 1);
        pairs[pos] = make_int2(p.x & COL_MASK, p.y);
    }
    if (b == 0 && tid == 0) offsets[n_total] = coff2[nb];
}

// ---------------------------------------------------------------------------
// gather spmm (bf16 src/dst, f32 accum): ONE 8-LANE GROUP PER ROW.
// Edge counts are padded to multiples of 4 -> pure 8/4-unrolled, NO serial tail.
__global__ void spmm_gather_kernel(const int* __restrict__ offsets,
                                   const int2* __restrict__ pairs,
                                   const unsigned short* __restrict__ src,
                                   unsigned short* __restrict__ dst, int n_total) {
    int t = blockIdx.x * blockDim.x + threadIdx.x;
    int r = t >> 3;          // destination row
    int sub = t & 7;         // 16 B slice of the row
    if (r >= n_total) return;
    int start = offsets[r];
    int end = offsets[r + 1];
    const uint4* s4 = reinterpret_cast<const uint4*>(src);
    float a0 = 0.f, a1 = 0.f, a2 = 0.f, a3 = 0.f,
          a4 = 0.f, a5 = 0.f, a6 = 0.f, a7 = 0.f;
    int k = start;
    for (; k + 8 <= end; k += 8) {
        int2 p[8];
        uint4 rr[8];
#pragma unroll
        for (int j = 0; j < 8; ++j) p[j] = pairs[k + j];
#pragma unroll
        for (int j = 0; j < 8; ++j) rr[j] = s4[(size_t)p[j].x * 8 + sub];
#pragma unroll
        for (int j = 0; j < 8; ++j) {
            float w = __int_as_float(p[j].y);
            a0 += w * bf_lo(rr[j].x); a1 += w * bf_hi(rr[j].x);
            a2 += w * bf_lo(rr[j].y); a3 += w * bf_hi(rr[j].y);
            a4 += w * bf_lo(rr[j].z); a5 += w * bf_hi(rr[j].z);
            a6 += w * bf_lo(rr[j].w); a7 += w * bf_hi(rr[j].w);
        }
    }
    if (k < end) {   // exactly 4 remain (padded)
        int2 p[4];
        uint4 rr[4];
#pragma unroll
        for (int j = 0; j < 4; ++j) p[j] = pairs[k + j];
#pragma unroll
        for (int j = 0; j < 4; ++j) rr[j] = s4[(size_t)p[j].x * 8 + sub];
#pragma unroll
        for (int j = 0; j < 4; ++j) {
            float w = __int_as_float(p[j].y);
            a0 += w * bf_lo(rr[j].x); a1 += w * bf_hi(rr[j].x);
            a2 += w * bf_lo(rr[j].y); a3 += w * bf_hi(rr[j].y);
            a4 += w * bf_lo(rr[j].z); a5 += w * bf_hi(rr[j].z);
            a6 += w * bf_lo(rr[j].w); a7 += w * bf_hi(rr[j].w);
        }
    }
    uint4 o;
    o.x = f2bf(a0) | (f2bf(a1) << 16);
    o.y = f2bf(a2) | (f2bf(a3) << 16);
    o.z = f2bf(a4) | (f2bf(a5) << 16);
    o.w = f2bf(a6) | (f2bf(a7) << 16);
    reinterpret_cast<uint4*>(dst + (size_t)r * D)[sub] = o;
}

// ---------------------------------------------------------------------------
// layer 0: write batch rows straight from the f32 source tables
__global__ void gather_init_kernel(const int* __restrict__ users,
                                   const int* __restrict__ items,
                                   const float* __restrict__ user_emb,
                                   const float* __restrict__ item_emb,
                                   float* __restrict__ u_acc,
                                   float* __restrict__ v_acc, int batch) {
    int t = blockIdx.x * blockDim.x + threadIdx.x;
    int b = t >> 4;
    int sub = t & 15;
    if (b >= batch) return;
    reinterpret_cast<float4*>(u_acc)[(size_t)b * 16 + sub] =
        reinterpret_cast<const float4*>(user_emb)[(size_t)users[b] * 16 + sub];
    reinterpret_cast<float4*>(v_acc)[(size_t)b * 16 + sub] =
        reinterpret_cast<const float4*>(item_emb)[(size_t)items[b] * 16 + sub];
}

// layers 1,2: accumulate batch rows from bf16 buf into f32 acc
__global__ void gather_acc_kernel(const int* __restrict__ users,
                                  const int* __restrict__ items,
                                  const unsigned short* __restrict__ buf,
                                  float* __restrict__ u_acc,
                                  float* __restrict__ v_acc,
                                  int batch, int n_user_rows) {
    int t = blockIdx.x * blockDim.x + threadIdx.x;
    int b = t >> 4;
    int sub = t & 15;
    if (b >= batch) return;
    uint2 ur = reinterpret_cast<const uint2*>(buf + (size_t)users[b] * D)[sub];
    uint2 vr = reinterpret_cast<const uint2*>(buf + (size_t)(n_user_rows + items[b]) * D)[sub];
    float4* up = reinterpret_cast<float4*>(u_acc) + (size_t)b * 16 + sub;
    float4* vp = reinterpret_cast<float4*>(v_acc) + (size_t)b * 16 + sub;
    float4 a = *up, c = *vp;
    a.x += bf_lo(ur.x); a.y += bf_hi(ur.x);
    a.z += bf_lo(ur.y); a.w += bf_hi(ur.y);
    c.x += bf_lo(vr.x); c.y += bf_hi(vr.x);
    c.z += bf_lo(vr.y); c.w += bf_hi(vr.y);
    *up = a;
    *vp = c;
}

// ---------------------------------------------------------------------------
// Fused final stage: per batch element, compute layer-3 ONLY for its user row
// and item row (4-unrolled, tail-free thanks to padding), add layer-0..2
// accumulators, dot, BCE, reduce.
__global__ void batch_l3_loss_kernel(const int* __restrict__ users,
                                     const int* __restrict__ items,
                                     const int* __restrict__ offsets,
                                     const int2* __restrict__ pairs,
                                     const unsigned short* __restrict__ buf,
                                     const float* __restrict__ u_acc,
                                     const float* __restrict__ v_acc,
                                     const float* __restrict__ labels,
                                     float* __restrict__ out,
                                     int batch, int n_user_rows) {
    int t = blockIdx.x * blockDim.x + threadIdx.x;
    int b = t >> 3;
    int sub = t & 7;
    const uint4* s4 = reinterpret_cast<const uint4*>(buf);
    float lb = 0.0f;
    if (b < batch) {
        float au[8] = {0.f}, av[8] = {0.f};
        for (int side = 0; side < 2; ++side) {
            int row = (side == 0) ? users[b] : (n_user_rows + items[b]);
            float* acc = (side == 0) ? au : av;
            int k = offsets[row];
            int end = offsets[row + 1];
            for (; k + 4 <= end; k += 4) {
                int2 p[4];
                uint4 rr[4];
#pragma unroll
                for (int j = 0; j < 4; ++j) p[j] = pairs[k + j];
#pragma unroll
                for (int j = 0; j < 4; ++j) rr[j] = s4[(size_t)p[j].x * 8 + sub];
#pragma unroll
                for (int j = 0; j < 4; ++j) {
                    float w = __int_as_float(p[j].y);
                    acc[0] += w * bf_lo(rr[j].x); acc[1] += w * bf_hi(rr[j].x);
                    acc[2] += w * bf_lo(rr[j].y); acc[3] += w * bf_hi(rr[j].y);
                    acc[4] += w * bf_lo(rr[j].z); acc[5] += w * bf_hi(rr[j].z);
                    acc[6] += w * bf_lo(rr[j].w); acc[7] += w * bf_hi(rr[j].w);
                }
            }
        }
        const float4* ua = reinterpret_cast<const float4*>(u_acc + (size_t)b * D);
        const float4* va = reinterpret_cast<const float4*>(v_acc + (size_t)b * D);
        float4 u0 = ua[sub * 2], u1 = ua[sub * 2 + 1];
        float4 v0 = va[sub * 2], v1 = va[sub * 2 + 1];
        float partial =
            (u0.x + au[0]) * (v0.x + av[0]) + (u0.y + au[1]) * (v0.y + av[1]) +
            (u0.z + au[2]) * (v0.z + av[2]) + (u0.w + au[3]) * (v0.w + av[3]) +
            (u1.x + au[4]) * (v1.x + av[4]) + (u1.y + au[5]) * (v1.y + av[5]) +
            (u1.z + au[6]) * (v1.z + av[6]) + (u1.w + au[7]) * (v1.w + av[7]);
        partial += __shfl_xor(partial, 1, 64);
        partial += __shfl_xor(partial, 2, 64);
        partial += __shfl_xor(partial, 4, 64);
        if (sub == 0) {
            float g = partial * (1.0f / 16.0f);
            float y = labels[b];
            lb = fmaxf(g, 0.0f) - g * y + log1pf(expf(-fabsf(g)));
        }
    }
    lb += __shfl_xor(lb, 8, 64);
    lb += __shfl_xor(lb, 16, 64);
    lb += __shfl_xor(lb, 32, 64);
    __shared__ float sd[4];
    int wid = threadIdx.x >> 6;
    if ((threadIdx.x & 63) == 0) sd[wid] = lb;
    __syncthreads();
    if (threadIdx.x == 0)
        atomicAdd(out, (sd[0] + sd[1] + sd[2] + sd[3]) / (float)batch);
}

// ---------------------------------------------------------------------------
extern "C" void kernel_launch(void* const* d_in, const int* in_sizes, int n_in,
                              void* d_out, int out_size, void* d_ws, size_t ws_size,
                              hipStream_t stream) {
    const int* users = (const int*)d_in[0];
    const int* items = (const int*)d_in[1];
    const float* labels = (const float*)d_in[2];
    const int* edge_row = (const int*)d_in[3];
    const int* edge_col = (const int*)d_in[4];
    const float* edge_val = (const float*)d_in[5];
    const float* user_emb = (const float*)d_in[6];
    const float* item_emb = (const float*)d_in[7];

    const int batch = in_sizes[0];
    const int n_edges = in_sizes[3];
    const int n_user_rows = in_sizes[6] / D;   // 100001
    const int n_item_rows = in_sizes[7] / D;   // 50000
    const int n_total = n_user_rows + n_item_rows;
    const int nb = (n_total + RB - 1) / RB;          // 293
    const int nblk = (n_edges + CHUNK - 1) / CHUNK;  // 489
    const int L = nb * nblk;                          // 143,277
    const int max_pairs = n_edges + 3 * nb * RB;      // padded upper bound

    auto align256 = [](size_t x) { return (x + 255) & ~(size_t)255; };
    const size_t tblb_bytes = align256((size_t)n_total * D * 2);            // 19.2 MB bf16
    const size_t acc_bytes = align256((size_t)batch * D * sizeof(float));   // 2 MB
    const size_t off_bytes = align256((size_t)(n_total + 1) * sizeof(int)); // 600 KB
    const size_t pairs_bytes = align256((size_t)max_pairs * sizeof(int2));  // ~19.6 MB
    const size_t hist_bytes = align256((size_t)L * sizeof(int));            // 573 KB
    const size_t coff_bytes = align256((size_t)(nb + 1) * sizeof(int));
    const size_t rowcnt_bytes = align256((size_t)nb * RB * sizeof(int));    // 600 KB

    char* ws = (char*)d_ws;
    unsigned short* tbl  = (unsigned short*)ws;  ws += tblb_bytes;
    unsigned short* buf0 = (unsigned short*)ws;  ws += tblb_bytes;
    unsigned short* buf1 = (unsigned short*)ws;  ws += tblb_bytes;
    float* u_acc  = (float*)ws;                  ws += acc_bytes;
    float* v_acc  = (float*)ws;                  ws += acc_bytes;
    int*   offsets= (int*)ws;                    ws += off_bytes;
    int2*  pairs  = (int2*)ws;                   ws += pairs_bytes;
    // stage (16 MB) dead before spmm layer 1 writes buf0 -> alias
    int2*  stage  = (int2*)buf0;
    // CSR-build scratch dead before spmm layer 2 writes buf1 -> alias
    char* sb = (char*)buf1;
    int* hist   = (int*)sb;                      sb += hist_bytes;
    int* tot    = (int*)sb;                      sb += coff_bytes;
    int* coff   = (int*)sb;                      sb += coff_bytes;
    int* tot2   = (int*)sb;                      sb += coff_bytes;
    int* coff2  = (int*)sb;                      sb += coff_bytes;
    int* rowcnt = (int*)sb;                      sb += rowcnt_bytes;

    hipMemsetAsync(d_out, 0, sizeof(float) * out_size, stream);

    // ---- bf16 table conversion ----
    convert_kernel<<<2048, 256, 0, stream>>>(user_emb, item_emb, tbl, n_user_rows, n_total);

    // ---- CSR build: exact-offset two-level binning + padded row slots ----
    hist2_kernel<<<nblk, FT, 0, stream>>>(edge_row, hist, n_edges, nb);
    const int wave_blocks = (nb + 3) / 4;
    col_sum_kernel<<<wave_blocks, 256, 0, stream>>>(hist, tot, nb, nblk);
    scan_tot_kernel<<<1, 256, 0, stream>>>(tot, coff, nb);
    col_scan_kernel<<<wave_blocks, 256, 0, stream>>>(hist, coff, nb, nblk);
    fill_exact_kernel<<<nblk, FT, 0, stream>>>(edge_row, edge_col, edge_val,
                                               hist, stage, n_edges, nb);
    bucket_count_kernel<<<nb, RB, 0, stream>>>(coff, stage, rowcnt, tot2);
    scan_tot_kernel<<<1, 256, 0, stream>>>(tot2, coff2, nb);
    bucket_scatter_kernel<<<nb, RB, 0, stream>>>(coff, coff2, rowcnt, stage,
                                                 offsets, pairs, n_total, nb);

    // ---- layer 0 batch gather ----
    const int ga_blocks = (batch * 16 + 255) / 256;
    gather_init_kernel<<<ga_blocks, 256, 0, stream>>>(users, items, user_emb, item_emb,
                                                      u_acc, v_acc, batch);

    // ---- layers 1,2 full propagation (bf16 gather, f32 accumulate) ----
    const int spmm_blocks = (int)(((size_t)n_total * 8 + 255) / 256);
    spmm_gather_kernel<<<spmm_blocks, 256, 0, stream>>>(offsets, pairs, tbl, buf0, n_total);
    gather_acc_kernel<<<ga_blocks, 256, 0, stream>>>(users, items, buf0,
                                                     u_acc, v_acc, batch, n_user_rows);
    spmm_gather_kernel<<<spmm_blocks, 256, 0, stream>>>(offsets, pairs, buf0, buf1, n_total);
    gather_acc_kernel<<<ga_blocks, 256, 0, stream>>>(users, items, buf1,
                                                     u_acc, v_acc, batch, n_user_rows);

    // ---- layer 3 computed ONLY at batch rows, fused with dot + BCE loss ----
    const int bl_blocks = (batch * 8 + 255) / 256;
    batch_l3_loss_kernel<<<bl_blocks, 256, 0, stream>>>(users, items, offsets, pairs,
                                                        buf1, u_acc, v_acc, labels,
                                                        (float*)d_out, batch, n_user_rows);
}

// Round 14
// 176.781 us; speedup vs baseline: 1.2234x; 1.0339x over previous
//
#include <hip/hip_runtime.h>
#include <hip/hip_bf16.h>

#define D 64
#define RB 512           // rows per coarse bucket (b = row>>9)
#define RB_SHIFT 9
#define COL_BITS 18      // n_total = 150001 < 2^18; row_local in bits 18..26
#define COL_MASK 0x3FFFF
#define CHUNK 4096       // edges per partition block (489 blocks)
#define FT 512           // threads for hist/fill kernels

// bf16 helpers (round-to-nearest-even; bf16->f32 exact)
__device__ __forceinline__ unsigned f2bf(float f) {
    unsigned u = __float_as_uint(f);
    u += 0x7fff + ((u >> 16) & 1);
    return u >> 16;
}
__device__ __forceinline__ float bf_lo(unsigned w) {
    return __uint_as_float(w << 16);
}
__device__ __forceinline__ float bf_hi(unsigned w) {
    return __uint_as_float(w & 0xffff0000u);
}

// ---------------------------------------------------------------------------
// FUSED: per-chunk bucket histogram (block-major hist[blk*nb+b]) + bf16 table
// conversion slice (grid-stride over the concat table).
__global__ void convhist_kernel(const float* __restrict__ user_emb,
                                const float* __restrict__ item_emb,
                                unsigned short* __restrict__ tbl,
                                int n_user_rows, int n_total,
                                const int* __restrict__ row,
                                int* __restrict__ hist, int n_edges, int nb) {
    __shared__ int h[RB];
    for (int i = threadIdx.x; i < nb; i += FT) h[i] = 0;
    __syncthreads();
    int blk = blockIdx.x;
    int s = blk * CHUNK;
    int e = min(s + CHUNK, n_edges);
    for (int k = s + threadIdx.x; k < e; k += FT)
        atomicAdd(&h[row[k] >> RB_SHIFT], 1);
    __syncthreads();
    for (int i = threadIdx.x; i < nb; i += FT)
        hist[blk * nb + i] = h[i];   // coalesced row write
    // conversion slice
    size_t t = (size_t)blk * FT + threadIdx.x;
    size_t total4 = (size_t)n_total * (D / 4);
    size_t user4 = (size_t)n_user_rows * (D / 4);
    size_t stride = (size_t)gridDim.x * FT;
    for (size_t i = t; i < total4; i += stride) {
        float4 v = (i < user4) ? reinterpret_cast<const float4*>(user_emb)[i]
                               : reinterpret_cast<const float4*>(item_emb)[i - user4];
        uint2 o;
        o.x = f2bf(v.x) | (f2bf(v.y) << 16);
        o.y = f2bf(v.z) | (f2bf(v.w) << 16);
        reinterpret_cast<uint2*>(tbl)[i] = o;
    }
}

// ---------------------------------------------------------------------------
// FUSED col_sum + scan + col_scan: ONE WAVE per bucket. Sums the bucket's
// column, atomically reserves a contiguous stage span, then column-scans
// hist[blk][b] into exact per-(block,bucket) write bases.
__global__ void col_alloc_kernel(int* __restrict__ hist,
                                 int* __restrict__ cstart, int* __restrict__ cend,
                                 int* __restrict__ cursor, int nb, int nblk) {
    int w = (blockIdx.x * blockDim.x + threadIdx.x) >> 6;
    int lane = threadIdx.x & 63;
    if (w >= nb) return;
    int ssum = 0;
    for (int blk = lane; blk < nblk; blk += 64)
        ssum += hist[blk * nb + w];
    for (int off = 32; off > 0; off >>= 1)
        ssum += __shfl_down(ssum, off, 64);
    int base = 0;
    if (lane == 0) base = atomicAdd(cursor, ssum);
    base = __shfl(base, 0, 64);
    int total = __shfl(ssum, 0, 64);
    if (lane == 0) { cstart[w] = base; cend[w] = base + total; }
    int run = base;
    for (int b0 = 0; b0 < nblk; b0 += 64) {
        int blk = b0 + lane;
        int v = (blk < nblk) ? hist[blk * nb + w] : 0;
        int inc = v;
#pragma unroll
        for (int off = 1; off < 64; off <<= 1) {
            int t = __shfl_up(inc, off, 64);
            if (lane >= off) inc += t;
        }
        if (blk < nblk) hist[blk * nb + w] = run + (inc - v);
        run += __shfl(inc, 63, 64);   // chunk total
    }
}

// ---------------------------------------------------------------------------
// Pass C: rank via block-private LDS cursors, write to exact positions
__global__ void fill_exact_kernel(const int* __restrict__ row, const int* __restrict__ col,
                                  const float* __restrict__ val, const int* __restrict__ hist,
                                  int2* __restrict__ stage, int n_edges, int nb) {
    __shared__ int cur[RB];
    int blk = blockIdx.x;
    for (int i = threadIdx.x; i < nb; i += FT)
        cur[i] = hist[blk * nb + i];   // coalesced row read
    __syncthreads();
    int s = blk * CHUNK;
    int e = min(s + CHUNK, n_edges);
    for (int k = s + threadIdx.x; k < e; k += FT) {
        int r = row[k];
        int b = r >> RB_SHIFT;
        int pos = atomicAdd(&cur[b], 1);
        stage[pos] = make_int2(col[k] | ((r & (RB - 1)) << COL_BITS), __float_as_int(val[k]));
    }
}

// ---------------------------------------------------------------------------
// FUSED bucket finalize: row histogram -> padded scan -> atomic span alloc ->
// per-row {start,end} (int2) -> pad fill -> row-sorted scatter. One pass, no
// global rowcnt round-trip.
__global__ void bucket_pad_kernel(const int* __restrict__ cstart,
                                  const int* __restrict__ cend,
                                  const int2* __restrict__ stage,
                                  int2* __restrict__ offs,
                                  int2* __restrict__ pairs,
                                  int* __restrict__ cursor, int n_total) {
    __shared__ int sc[RB];
    __shared__ int cur[RB];
    __shared__ int pbase_s;
    int b = blockIdx.x;
    int tid = threadIdx.x;
    int s = cstart[b], e = cend[b];
    sc[tid] = 0;
    __syncthreads();
    for (int k = s + tid; k < e; k += RB)
        atomicAdd(&sc[stage[k].x >> COL_BITS], 1);
    __syncthreads();
    int cnt = sc[tid];
    int pad = (cnt + 3) & ~3;
    __syncthreads();
    sc[tid] = pad;
    __syncthreads();
    for (int off = 1; off < RB; off <<= 1) {
        int v = (tid >= off) ? sc[tid - off] : 0;
        __syncthreads();
        sc[tid] += v;
        __syncthreads();
    }
    if (tid == RB - 1) pbase_s = atomicAdd(cursor, sc[RB - 1]);
    __syncthreads();
    int start = pbase_s + sc[tid] - pad;   // exclusive padded prefix
    int r = b * RB + tid;
    if (r < n_total) offs[r] = make_int2(start, start + pad);
    cur[tid] = start;
    for (int q = start + cnt; q < start + pad; ++q)
        pairs[q] = make_int2(0, 0);   // col 0, weight 0.0f
    __syncthreads();
    for (int k = s + tid; k < e; k += RB) {
        int2 p = stage[k];
        int rl = p.x >> COL_BITS;
        int pos = atomicAdd(&cur[rl], 1);
        pairs[pos] = make_int2(p.x & COL_MASK, p.y);
    }
}

// ---------------------------------------------------------------------------
// gather spmm (bf16 src/dst, f32 accum): ONE 8-LANE GROUP PER ROW.
// Edge counts are padded to multiples of 4 -> pure 8/4-unrolled, NO serial tail.
__global__ void spmm_gather_kernel(const int2* __restrict__ offs,
                                   const int2* __restrict__ pairs,
                                   const unsigned short* __restrict__ src,
                                   unsigned short* __restrict__ dst, int n_total) {
    int t = blockIdx.x * blockDim.x + threadIdx.x;
    int r = t >> 3;          // destination row
    int sub = t & 7;         // 16 B slice of the row
    if (r >= n_total) return;
    int2 oo = offs[r];
    int k = oo.x;
    int end = oo.y;
    const uint4* s4 = reinterpret_cast<const uint4*>(src);
    float a0 = 0.f, a1 = 0.f, a2 = 0.f, a3 = 0.f,
          a4 = 0.f, a5 = 0.f, a6 = 0.f, a7 = 0.f;
    for (; k + 8 <= end; k += 8) {
        int2 p[8];
        uint4 rr[8];
#pragma unroll
        for (int j = 0; j < 8; ++j) p[j] = pairs[k + j];
#pragma unroll
        for (int j = 0; j < 8; ++j) rr[j] = s4[(size_t)p[j].x * 8 + sub];
#pragma unroll
        for (int j = 0; j < 8; ++j) {
            float w = __int_as_float(p[j].y);
            a0 += w * bf_lo(rr[j].x); a1 += w * bf_hi(rr[j].x);
            a2 += w * bf_lo(rr[j].y); a3 += w * bf_hi(rr[j].y);
            a4 += w * bf_lo(rr[j].z); a5 += w * bf_hi(rr[j].z);
            a6 += w * bf_lo(rr[j].w); a7 += w * bf_hi(rr[j].w);
        }
    }
    if (k < end) {   // exactly 4 remain (padded)
        int2 p[4];
        uint4 rr[4];
#pragma unroll
        for (int j = 0; j < 4; ++j) p[j] = pairs[k + j];
#pragma unroll
        for (int j = 0; j < 4; ++j) rr[j] = s4[(size_t)p[j].x * 8 + sub];
#pragma unroll
        for (int j = 0; j < 4; ++j) {
            float w = __int_as_float(p[j].y);
            a0 += w * bf_lo(rr[j].x); a1 += w * bf_hi(rr[j].x);
            a2 += w * bf_lo(rr[j].y); a3 += w * bf_hi(rr[j].y);
            a4 += w * bf_lo(rr[j].z); a5 += w * bf_hi(rr[j].z);
            a6 += w * bf_lo(rr[j].w); a7 += w * bf_hi(rr[j].w);
        }
    }
    uint4 o;
    o.x = f2bf(a0) | (f2bf(a1) << 16);
    o.y = f2bf(a2) | (f2bf(a3) << 16);
    o.z = f2bf(a4) | (f2bf(a5) << 16);
    o.w = f2bf(a6) | (f2bf(a7) << 16);
    reinterpret_cast<uint4*>(dst + (size_t)r * D)[sub] = o;
}

// ---------------------------------------------------------------------------
// FUSED layers 0+1 batch gather: u_acc = user_emb[u] (f32) + buf0[u] (bf16);
// same for items. Pure store, no read-modify-write.
__global__ void gather_init_acc_kernel(const int* __restrict__ users,
                                       const int* __restrict__ items,
                                       const float* __restrict__ user_emb,
                                       const float* __restrict__ item_emb,
                                       const unsigned short* __restrict__ buf,
                                       float* __restrict__ u_acc,
                                       float* __restrict__ v_acc,
                                       int batch, int n_user_rows) {
    int t = blockIdx.x * blockDim.x + threadIdx.x;
    int b = t >> 4;
    int sub = t & 15;
    if (b >= batch) return;
    int u = users[b];
    int it = items[b];
    float4 a = reinterpret_cast<const float4*>(user_emb)[(size_t)u * 16 + sub];
    float4 c = reinterpret_cast<const float4*>(item_emb)[(size_t)it * 16 + sub];
    uint2 ur = reinterpret_cast<const uint2*>(buf + (size_t)u * D)[sub];
    uint2 vr = reinterpret_cast<const uint2*>(buf + (size_t)(n_user_rows + it) * D)[sub];
    a.x += bf_lo(ur.x); a.y += bf_hi(ur.x);
    a.z += bf_lo(ur.y); a.w += bf_hi(ur.y);
    c.x += bf_lo(vr.x); c.y += bf_hi(vr.x);
    c.z += bf_lo(vr.y); c.w += bf_hi(vr.y);
    reinterpret_cast<float4*>(u_acc)[(size_t)b * 16 + sub] = a;
    reinterpret_cast<float4*>(v_acc)[(size_t)b * 16 + sub] = c;
}

// layer 2: accumulate batch rows from bf16 buf into f32 acc
__global__ void gather_acc_kernel(const int* __restrict__ users,
                                  const int* __restrict__ items,
                                  const unsigned short* __restrict__ buf,
                                  float* __restrict__ u_acc,
                                  float* __restrict__ v_acc,
                                  int batch, int n_user_rows) {
    int t = blockIdx.x * blockDim.x + threadIdx.x;
    int b = t >> 4;
    int sub = t & 15;
    if (b >= batch) return;
    uint2 ur = reinterpret_cast<const uint2*>(buf + (size_t)users[b] * D)[sub];
    uint2 vr = reinterpret_cast<const uint2*>(buf + (size_t)(n_user_rows + items[b]) * D)[sub];
    float4* up = reinterpret_cast<float4*>(u_acc) + (size_t)b * 16 + sub;
    float4* vp = reinterpret_cast<float4*>(v_acc) + (size_t)b * 16 + sub;
    float4 a = *up, c = *vp;
    a.x += bf_lo(ur.x); a.y += bf_hi(ur.x);
    a.z += bf_lo(ur.y); a.w += bf_hi(ur.y);
    c.x += bf_lo(vr.x); c.y += bf_hi(vr.x);
    c.z += bf_lo(vr.y); c.w += bf_hi(vr.y);
    *up = a;
    *vp = c;
}

// ---------------------------------------------------------------------------
// Fused final stage: per batch element, compute layer-3 ONLY for its user row
// and item row (4-unrolled, tail-free thanks to padding), add layer-0..2
// accumulators, dot, BCE, reduce.
__global__ void batch_l3_loss_kernel(const int* __restrict__ users,
                                     const int* __restrict__ items,
                                     const int2* __restrict__ offs,
                                     const int2* __restrict__ pairs,
                                     const unsigned short* __restrict__ buf,
                                     const float* __restrict__ u_acc,
                                     const float* __restrict__ v_acc,
                                     const float* __restrict__ labels,
                                     float* __restrict__ out,
                                     int batch, int n_user_rows) {
    int t = blockIdx.x * blockDim.x + threadIdx.x;
    int b = t >> 3;
    int sub = t & 7;
    const uint4* s4 = reinterpret_cast<const uint4*>(buf);
    float lb = 0.0f;
    if (b < batch) {
        float au[8] = {0.f}, av[8] = {0.f};
        for (int side = 0; side < 2; ++side) {
            int row = (side == 0) ? users[b] : (n_user_rows + items[b]);
            float* acc = (side == 0) ? au : av;
            int2 oo = offs[row];
            for (int k = oo.x; k + 4 <= oo.y; k += 4) {
                int2 p[4];
                uint4 rr[4];
#pragma unroll
                for (int j = 0; j < 4; ++j) p[j] = pairs[k + j];
#pragma unroll
                for (int j = 0; j < 4; ++j) rr[j] = s4[(size_t)p[j].x * 8 + sub];
#pragma unroll
                for (int j = 0; j < 4; ++j) {
                    float w = __int_as_float(p[j].y);
                    acc[0] += w * bf_lo(rr[j].x); acc[1] += w * bf_hi(rr[j].x);
                    acc[2] += w * bf_lo(rr[j].y); acc[3] += w * bf_hi(rr[j].y);
                    acc[4] += w * bf_lo(rr[j].z); acc[5] += w * bf_hi(rr[j].z);
                    acc[6] += w * bf_lo(rr[j].w); acc[7] += w * bf_hi(rr[j].w);
                }
            }
        }
        const float4* ua = reinterpret_cast<const float4*>(u_acc + (size_t)b * D);
        const float4* va = reinterpret_cast<const float4*>(v_acc + (size_t)b * D);
        float4 u0 = ua[sub * 2], u1 = ua[sub * 2 + 1];
        float4 v0 = va[sub * 2], v1 = va[sub * 2 + 1];
        float partial =
            (u0.x + au[0]) * (v0.x + av[0]) + (u0.y + au[1]) * (v0.y + av[1]) +
            (u0.z + au[2]) * (v0.z + av[2]) + (u0.w + au[3]) * (v0.w + av[3]) +
            (u1.x + au[4]) * (v1.x + av[4]) + (u1.y + au[5]) * (v1.y + av[5]) +
            (u1.z + au[6]) * (v1.z + av[6]) + (u1.w + au[7]) * (v1.w + av[7]);
        partial += __shfl_xor(partial, 1, 64);
        partial += __shfl_xor(partial, 2, 64);
        partial += __shfl_xor(partial, 4, 64);
        if (sub == 0) {
            float g = partial * (1.0f / 16.0f);
            float y = labels[b];
            lb = fmaxf(g, 0.0f) - g * y + log1pf(expf(-fabsf(g)));
        }
    }
    lb += __shfl_xor(lb, 8, 64);
    lb += __shfl_xor(lb, 16, 64);
    lb += __shfl_xor(lb, 32, 64);
    __shared__ float sd[4];
    int wid = threadIdx.x >> 6;
    if ((threadIdx.x & 63) == 0) sd[wid] = lb;
    __syncthreads();
    if (threadIdx.x == 0)
        atomicAdd(out, (sd[0] + sd[1] + sd[2] + sd[3]) / (float)batch);
}

// ---------------------------------------------------------------------------
extern "C" void kernel_launch(void* const* d_in, const int* in_sizes, int n_in,
                              void* d_out, int out_size, void* d_ws, size_t ws_size,
                              hipStream_t stream) {
    const int* users = (const int*)d_in[0];
    const int* items = (const int*)d_in[1];
    const float* labels = (const float*)d_in[2];
    const int* edge_row = (const int*)d_in[3];
    const int* edge_col = (const int*)d_in[4];
    const float* edge_val = (const float*)d_in[5];
    const float* user_emb = (const float*)d_in[6];
    const float* item_emb = (const float*)d_in[7];

    const int batch = in_sizes[0];
    const int n_edges = in_sizes[3];
    const int n_user_rows = in_sizes[6] / D;   // 100001
    const int n_item_rows = in_sizes[7] / D;   // 50000
    const int n_total = n_user_rows + n_item_rows;
    const int nb = (n_total + RB - 1) / RB;          // 293
    const int nblk = (n_edges + CHUNK - 1) / CHUNK;  // 489
    const int L = nb * nblk;                          // 143,277
    const int max_pairs = n_edges + 3 * nb * RB;      // padded upper bound

    auto align256 = [](size_t x) { return (x + 255) & ~(size_t)255; };
    const size_t tblb_bytes = align256((size_t)n_total * D * 2);            // 19.2 MB bf16
    const size_t acc_bytes = align256((size_t)batch * D * sizeof(float));   // 2 MB
    const size_t offs_bytes = align256((size_t)n_total * sizeof(int2));     // 1.2 MB
    const size_t pairs_bytes = align256((size_t)max_pairs * sizeof(int2));  // ~19.6 MB
    const size_t hist_bytes = align256((size_t)L * sizeof(int));            // 573 KB
    const size_t cse_bytes = align256((size_t)nb * sizeof(int));

    char* ws = (char*)d_ws;
    unsigned short* tbl  = (unsigned short*)ws;  ws += tblb_bytes;
    unsigned short* buf0 = (unsigned short*)ws;  ws += tblb_bytes;
    unsigned short* buf1 = (unsigned short*)ws;  ws += tblb_bytes;
    float* u_acc  = (float*)ws;                  ws += acc_bytes;
    float* v_acc  = (float*)ws;                  ws += acc_bytes;
    int2*  offs   = (int2*)ws;                   ws += offs_bytes;
    int2*  pairs  = (int2*)ws;                   ws += pairs_bytes;
    int*   cursor = (int*)ws;                    ws += 256;
    // stage (16 MB) dead before spmm layer 1 writes buf0 -> alias
    int2*  stage  = (int2*)buf0;
    // CSR-build scratch dead before spmm layer 2 writes buf1 -> alias
    char* sb = (char*)buf1;
    int* hist   = (int*)sb;                      sb += hist_bytes;
    int* cstart = (int*)sb;                      sb += cse_bytes;
    int* cend   = (int*)sb;                      sb += cse_bytes;

    hipMemsetAsync(d_out, 0, sizeof(float) * out_size, stream);
    hipMemsetAsync(cursor, 0, 2 * sizeof(int), stream);

    // ---- fused bf16 conversion + per-chunk histogram ----
    convhist_kernel<<<nblk, FT, 0, stream>>>(user_emb, item_emb, tbl,
                                             n_user_rows, n_total,
                                             edge_row, hist, n_edges, nb);

    // ---- fused column alloc+scan (atomic span allocation per bucket) ----
    const int wave_blocks = (nb + 3) / 4;
    col_alloc_kernel<<<wave_blocks, 256, 0, stream>>>(hist, cstart, cend,
                                                      &cursor[0], nb, nblk);
    fill_exact_kernel<<<nblk, FT, 0, stream>>>(edge_row, edge_col, edge_val,
                                               hist, stage, n_edges, nb);
    bucket_pad_kernel<<<nb, RB, 0, stream>>>(cstart, cend, stage, offs, pairs,
                                             &cursor[1], n_total);

    // ---- layers 1,2 full propagation (bf16 gather, f32 accumulate) ----
    const int ga_blocks = (batch * 16 + 255) / 256;
    const int spmm_blocks = (int)(((size_t)n_total * 8 + 255) / 256);
    spmm_gather_kernel<<<spmm_blocks, 256, 0, stream>>>(offs, pairs, tbl, buf0, n_total);
    gather_init_acc_kernel<<<ga_blocks, 256, 0, stream>>>(users, items, user_emb,
                                                          item_emb, buf0, u_acc, v_acc,
                                                          batch, n_user_rows);
    spmm_gather_kernel<<<spmm_blocks, 256, 0, stream>>>(offs, pairs, buf0, buf1, n_total);
    gather_acc_kernel<<<ga_blocks, 256, 0, stream>>>(users, items, buf1,
                                                     u_acc, v_acc, batch, n_user_rows);

    // ---- layer 3 computed ONLY at batch rows, fused with dot + BCE loss ----
    const int bl_blocks = (batch * 8 + 255) / 256;
    batch_l3_loss_kernel<<<bl_blocks, 256, 0, stream>>>(users, items, offs, pairs,
                                                        buf1, u_acc, v_acc, labels,
                                                        (float*)d_out, batch, n_user_rows);
}